// Round 11
// baseline (1983.344 us; speedup 1.0000x reference)
//
#include <hip/hip_runtime.h>

#define EPSF 1e-8f

typedef __attribute__((ext_vector_type(8))) short short8;
typedef __attribute__((ext_vector_type(4))) short short4v;
typedef __attribute__((ext_vector_type(4))) float float4v;

// ---- fp32 -> bf16 hi/lo split (RNE) ---------------------------------------
__device__ __forceinline__ unsigned bfhi_bits(float x) {
    unsigned u = __float_as_uint(x);
    return (u + 0x7fffu + ((u >> 16) & 1u)) >> 16;
}
__device__ __forceinline__ float bits2f(unsigned b) { return __uint_as_float(b << 16); }
__device__ __forceinline__ void split_bf(float x, unsigned short& h, unsigned short& l) {
    unsigned hb = bfhi_bits(x);
    h = (unsigned short)hb;
    l = (unsigned short)bfhi_bits(x - bits2f(hb));
}

// ---------------------------------------------------------------------------
// matvec3_v: acc[t] += sum_h wrow[h] * prow[h*3+t], NH entries (mult of 4),
// prow 16B-aligned LDS. float4 loads; per-accumulator fma order identical to
// the scalar h-loop (h strictly increasing) -> bit-identical results.
// ---------------------------------------------------------------------------
template<int NH>
__device__ __forceinline__ void matvec3_v(const float* __restrict__ wrow,
                                          const float* prow,
                                          float& a0, float& a1, float& a2)
{
    #pragma unroll
    for (int g = 0; g < NH / 4; ++g) {
        const float4 f0 = ((const float4*)prow)[3 * g + 0];
        const float4 f1 = ((const float4*)prow)[3 * g + 1];
        const float4 f2 = ((const float4*)prow)[3 * g + 2];
        const float w0 = wrow[4 * g + 0], w1 = wrow[4 * g + 1];
        const float w2 = wrow[4 * g + 2], w3 = wrow[4 * g + 3];
        a0 = fmaf(w0, f0.x, a0); a1 = fmaf(w0, f0.y, a1); a2 = fmaf(w0, f0.z, a2);
        a0 = fmaf(w1, f0.w, a0); a1 = fmaf(w1, f1.x, a1); a2 = fmaf(w1, f1.y, a2);
        a0 = fmaf(w2, f1.z, a0); a1 = fmaf(w2, f1.w, a1); a2 = fmaf(w2, f2.x, a2);
        a0 = fmaf(w3, f2.y, a0); a1 = fmaf(w3, f2.z, a1); a2 = fmaf(w3, f2.w, a2);
    }
}

// ---------------------------------------------------------------------------
// Pack W[NO][K] fp32 (row-major) into MFMA B-fragment order, bf16 hi/lo.
// ---------------------------------------------------------------------------
__global__ void pack_w(const float* __restrict__ W, unsigned short* __restrict__ hi,
                       unsigned short* __restrict__ lo, int NO, int K, int steps) {
    const int gid = blockIdx.x * 256 + threadIdx.x;
    const int total = (NO >> 4) * steps * 512;
    if (gid >= total) return;
    const int j = gid & 7, l = (gid >> 3) & 63, rest = gid >> 9;
    const int t = rest % steps, nt = rest / steps;
    const int n = nt * 16 + (l & 15);
    const int k = t * 32 + ((l >> 4) << 3) + j;
    const float x = (k < K) ? W[(size_t)n * K + k] : 0.f;
    unsigned short h, lw;
    split_bf(x, h, lw);
    hi[gid] = h; lo[gid] = lw;
}

// pack m1 edge-part B: NO=128, K=96, steps=3.
__global__ void pack_m1e(const float* __restrict__ W, unsigned short* __restrict__ hi,
                         unsigned short* __restrict__ lo) {
    const int gid = blockIdx.x * 256 + threadIdx.x;
    if (gid >= 12288) return;
    const int j = gid & 7, l = (gid >> 3) & 63, rest = gid >> 9;
    const int t = rest % 3, nt = rest / 3;
    const int n = nt * 16 + (l & 15);
    const int k = t * 32 + ((l >> 4) << 3) + j;
    float x = 0.f;
    if (k < 32)      x = W[(size_t)n * 321 + 128 + k];
    else if (k < 65) x = W[(size_t)n * 321 + 288 + (k - 32)];
    unsigned short h, lw; split_bf(x, h, lw);
    hi[gid] = h; lo[gid] = lw;
}

// pack node-pre B: NO=256, K=128, steps=4.
__global__ void pack_m1n(const float* __restrict__ W, unsigned short* __restrict__ hi,
                         unsigned short* __restrict__ lo) {
    const int gid = blockIdx.x * 256 + threadIdx.x;
    if (gid >= 32768) return;
    const int j = gid & 7, l = (gid >> 3) & 63, rest = gid >> 9;
    const int t = rest & 3, nt = rest >> 2;
    const int n = nt * 16 + (l & 15);
    const int k = t * 32 + ((l >> 4) << 3) + j;
    const float x = (n < 128) ? W[(size_t)n * 321 + k]
                              : W[(size_t)(n - 128) * 321 + 160 + k];
    unsigned short h, lw; split_bf(x, h, lw);
    hi[gid] = h; lo[gid] = lw;
}

// ---------------------------------------------------------------------------
// 3-pass split-bf16 MFMA K-loop (validated).  MCLAMP masks the A-row index
// (use 7 when the A buffer has only 8 rows: lanes 8-15 re-read rows 0-7,
// producing garbage-but-finite C rows 8-15 that the caller discards).
// ---------------------------------------------------------------------------
template<int STEPS, int NTPW, int ASTR, int MCLAMP = 15>
__device__ __forceinline__ void kloop(const unsigned short* PAh, const unsigned short* PAl,
    const unsigned short* __restrict__ wph, const unsigned short* __restrict__ wpl,
    float4v* acc, int lane, int wave)
{
    const int m = (lane & 15) & MCLAMP, q = lane >> 4;
    for (int t = 0; t < STEPS; ++t) {
        const int k0 = t * 32 + q * 8;
        const short8 ah = *(const short8*)(PAh + m * ASTR + k0);
        const short8 al = *(const short8*)(PAl + m * ASTR + k0);
        #pragma unroll
        for (int i = 0; i < NTPW; ++i) {
            const int nt = wave * NTPW + i;
            const size_t off = ((size_t)(nt * STEPS + t) * 64 + lane) * 8;
            const short8 bh = *(const short8*)(wph + off);
            const short8 bl = *(const short8*)(wpl + off);
            acc[i] = __builtin_amdgcn_mfma_f32_16x16x32_bf16(ah, bh, acc[i], 0, 0, 0);
            acc[i] = __builtin_amdgcn_mfma_f32_16x16x32_bf16(al, bh, acc[i], 0, 0, 0);
            acc[i] = __builtin_amdgcn_mfma_f32_16x16x32_bf16(ah, bl, acc[i], 0, 0, 0);
        }
    }
}

// ===========================================================================
// node_pre (green in R5, verbatim)
// ===========================================================================
constexpr int PAS = 136;

__global__ __launch_bounds__(256)
void node_pre(const float* __restrict__ s, const float* __restrict__ v,
              const float* __restrict__ m1_wh, const float* __restrict__ m1_wsb,
              const unsigned short* __restrict__ pnh, const unsigned short* __restrict__ pnl,
              float* __restrict__ Pg, float* __restrict__ Q1g, float* __restrict__ Q3g,
              int N)
{
    __shared__ __align__(16) unsigned short Ah[16 * PAS], Al[16 * PAS];
    __shared__ __align__(16) float Vs[16 * 48];

    const int tid = threadIdx.x, lane = tid & 63, wave = tid >> 6;
    const int e = tid & 15, q16 = tid >> 4;
    const int n0 = blockIdx.x * 16;
    const int ne = min(n0 + e, N - 1);

    {
        const float* sp = s + (size_t)ne * 128 + q16 * 8;
        const float4 x = ((const float4*)sp)[0];
        const float4 y = ((const float4*)sp)[1];
        short8 hv, lv; unsigned short h, l;
        split_bf(x.x, h, l); hv[0] = h; lv[0] = l;
        split_bf(x.y, h, l); hv[1] = h; lv[1] = l;
        split_bf(x.z, h, l); hv[2] = h; lv[2] = l;
        split_bf(x.w, h, l); hv[3] = h; lv[3] = l;
        split_bf(y.x, h, l); hv[4] = h; lv[4] = l;
        split_bf(y.y, h, l); hv[5] = h; lv[5] = l;
        split_bf(y.z, h, l); hv[6] = h; lv[6] = l;
        split_bf(y.w, h, l); hv[7] = h; lv[7] = l;
        *(short8*)(Ah + e * PAS + q16 * 8) = hv;
        *(short8*)(Al + e * PAS + q16 * 8) = lv;
    }
    if (q16 < 12)
        ((float4*)(Vs + e * 48))[q16] = ((const float4*)(v + (size_t)ne * 48))[q16];
    __syncthreads();

    {
        float4v acc[4] = {{0,0,0,0},{0,0,0,0},{0,0,0,0},{0,0,0,0}};
        kloop<4, 4, PAS>(Ah, Al, pnh, pnl, acc, lane, wave);
        const int q = lane >> 4;
        #pragma unroll
        for (int i = 0; i < 4; ++i) {
            const int j = (wave * 4 + i) * 16 + (lane & 15);
            const float bias = (j < 128) ? m1_wsb[j] : 0.f;
            #pragma unroll
            for (int r = 0; r < 4; ++r) {
                const int m = q * 4 + r;
                if (n0 + m < N) Pg[(size_t)(n0 + m) * 256 + j] = acc[i][r] + bias;
            }
        }
    }
    #pragma unroll
    for (int k = 0; k < 7; ++k) {
        const int idx = tid + k * 256;
        if (idx < 16 * 99) {
            const int n = idx & 15, j = idx >> 4;
            const int h = j / 3, t = j - h * 3;
            const float* vb = Vs + n * 48 + t;
            const float* w = m1_wh + h * 33;
            float a1 = 0.f, a3 = 0.f;
            for (int c = 0; c < 16; ++c) {
                const float vv = vb[c * 3];
                a1 = fmaf(w[c], vv, a1);
                a3 = fmaf(w[17 + c], vv, a3);
            }
            const int nn = n0 + n;
            if (nn < N) {
                Q1g[(size_t)nn * 100 + j] = a1;
                Q3g[(size_t)nn * 100 + j] = a3;
            }
        }
    }
}

// ---------------------------------------------------------------------------
// Edge kernel (RESTRUCTURED): 8 edges / block, 64 threads = ONE WAVE.
// All phases are wave-private: __syncthreads() in a 1-wave block costs ~0
// (no inter-wave wait), and intra-wave LDS ordering is program-order.
// The cross-wave race class is structurally impossible.  Per-edge arithmetic
// is verbatim R10-green; only the lane->task maps changed (e=lane&7,
// q8=lane>>3).  MFMA kloops use NTPW=8 + MCLAMP=7 (8 valid A rows; C rows
// 8-15 discarded -- proven pattern from R10's node f2).
// LDS = 12928 B -> 12 blocks/CU = 12 independent wave-chains.
// Overlays (PB==A, B2 in SP) ordered by program order within the wave.
// fp64-atomic aggregation (deterministic) unchanged.
// ---------------------------------------------------------------------------
constexpr int SA2 = 168;
constexpr int SBs = 168;
constexpr int SB1 = 100;
constexpr int SB2 = 52;
constexpr int SPS = 132;

__global__ __launch_bounds__(64)
void edge_kernel(const int* __restrict__ eidx,
                 const float* __restrict__ es, const float* __restrict__ ev,
                 const float* __restrict__ m1_wh, const float* __restrict__ m1_wv,
                 const float* __restrict__ m2_wh, const float* __restrict__ m2_wsb,
                 const float* __restrict__ m2_wv,
                 const float* __restrict__ m3_wh, const float* __restrict__ m3_wsb,
                 const float* __restrict__ m3_wv,
                 const unsigned short* __restrict__ p1h, const unsigned short* __restrict__ p1l,
                 const unsigned short* __restrict__ p2h, const unsigned short* __restrict__ p2l,
                 const unsigned short* __restrict__ p3h, const unsigned short* __restrict__ p3l,
                 const float* __restrict__ Pg, const float* __restrict__ Q1g,
                 const float* __restrict__ Q3g,
                 double* __restrict__ agg_s, double* __restrict__ agg_v,
                 float* __restrict__ cnt, int E)
{
    __shared__ __align__(16) unsigned short Ah[8 * SA2], Al[8 * SA2];
    __shared__ __align__(16) float SP[8 * SPS];
    __shared__ __align__(16) float B1[8 * SB1];
    __shared__ int ssrc[8], sgd[8], sdst[8], seid[8];

    unsigned short* PBh = Ah;      // overlay: PB == A (identical geometry)
    unsigned short* PBl = Al;
    float* B2 = SP;                // overlay: B2 in SP's first 1664 B

    const int lane = threadIdx.x & 63;
    const int e = lane & 7, q8 = lane >> 3;
    const int e0 = blockIdx.x * 8;

    // per-thread index regs (pre-barrier gathers)
    const int eg_r = e0 + e;
    const int ee_r = (eg_r < E) ? eg_r : (E - 1);
    const int src_r = eidx[ee_r];
    const int dst_r = eidx[E + ee_r];

    // E2a: es -> A[0,32) bf16 (all 64 lanes: edge e, cols 4*q8..4*q8+3)
    {
        const float4 x = ((const float4*)(es + (size_t)ee_r * 32))[q8];
        short4v hv, lv; unsigned short h, l;
        split_bf(x.x, h, l); hv[0] = h; lv[0] = l;
        split_bf(x.y, h, l); hv[1] = h; lv[1] = l;
        split_bf(x.z, h, l); hv[2] = h; lv[2] = l;
        split_bf(x.w, h, l); hv[3] = h; lv[3] = l;
        *(short4v*)(Ah + e * SA2 + 4 * q8) = hv;
        *(short4v*)(Al + e * SA2 + 4 * q8) = lv;
    }
    // zero pads cols [65,96)
    { const int c = 65 + q8; Ah[e * SA2 + c] = 0; Al[e * SA2 + c] = 0; }
    { const int c = 73 + q8; Ah[e * SA2 + c] = 0; Al[e * SA2 + c] = 0; }
    { const int c = 81 + q8; Ah[e * SA2 + c] = 0; Al[e * SA2 + c] = 0; }
    { const int c = 89 + q8; if (c < 96) { Ah[e * SA2 + c] = 0; Al[e * SA2 + c] = 0; } }
    // SP = P1[src]+P3[dst]  (16 f32/lane)
    {
        const float* P1 = Pg + (size_t)src_r * 256;
        const float* P3 = Pg + (size_t)dst_r * 256 + 128;
        #pragma unroll
        for (int j = 0; j < 4; ++j) {
            const float4 a = ((const float4*)P1)[4 * q8 + j];
            const float4 b = ((const float4*)P3)[4 * q8 + j];
            float4 r;
            r.x = a.x + b.x; r.y = a.y + b.y; r.z = a.z + b.z; r.w = a.w + b.w;
            ((float4*)(SP + e * SPS + 16 * q8))[j] = r;
        }
    }
    // E1: index table
    if (lane < 8) {
        const int eg = e0 + lane;
        const bool ok = (eg < E);
        const int ee = ok ? eg : (E - 1);
        seid[lane] = ee;
        ssrc[lane] = eidx[ee];
        const int d = eidx[E + ee];
        sgd[lane] = d;
        sdst[lane] = ok ? d : -1;
    }
    __syncthreads();

    // Q-loop: vh1 = Q1[src]+Q3[dst]+wh16*ev -> B1; vn1 -> A[32,65)
    #pragma unroll
    for (int k = 0; k < 5; ++k) {
        const int idx = lane + k * 64;
        if (idx < 264) {
            const int h = idx >> 3, e2 = idx & 7;
            const float* q1 = Q1g + (size_t)ssrc[e2] * 100 + h * 3;
            const float* q3 = Q3g + (size_t)sgd[e2] * 100 + h * 3;
            const float* evp = ev + (size_t)seid[e2] * 3;
            const float w16 = m1_wh[h * 33 + 16];
            const float v0 = q1[0] + q3[0] + w16 * evp[0];
            const float v1 = q1[1] + q3[1] + w16 * evp[1];
            const float v2 = q1[2] + q3[2] + w16 * evp[2];
            float* o = B1 + e2 * SB1 + h * 3;
            o[0] = v0; o[1] = v1; o[2] = v2;
            const float vn = sqrtf(fmaxf(v0 * v0 + v1 * v1 + v2 * v2, EPSF));
            unsigned short hh, ll; split_bf(vn, hh, ll);
            Ah[e2 * SA2 + 32 + h] = hh; Al[e2 * SA2 + 32 + h] = ll;
        }
    }
    __syncthreads();

    // E5a: m1 MFMA (K=96, 8 n-tiles, A rows clamped to 8)
    float4v acc1[8];
    #pragma unroll
    for (int i = 0; i < 8; ++i) acc1[i] = (float4v){0.f, 0.f, 0.f, 0.f};
    kloop<3, 8, SA2, 7>(Ah, Al, p1h, p1l, acc1, lane, 0);
    __syncthreads();

    // E5b: +SP -> relu -> PB(=A)[m<8][0,128)
    {
        const int q = lane >> 4;
        #pragma unroll
        for (int i = 0; i < 8; ++i) {
            const int n = i * 16 + (lane & 15);
            #pragma unroll
            for (int r = 0; r < 4; ++r) {
                const int m = q * 4 + r;
                if (m < 8) {
                    const float x = fmaxf(acc1[i][r] + SP[m * SPS + n], 0.f);
                    unsigned short h, l; split_bf(x, h, l);
                    PBh[m * SBs + n] = h; PBl[m * SBs + n] = l;
                }
            }
        }
    }
    __syncthreads();

    // E5c: vout1 -> B2(=SP)  (8 edges x 16 o = 2 iters)
    #pragma unroll
    for (int it = 0; it < 2; ++it) {
        const int o = q8 + 8 * it;
        const float* wrow = m1_wv + o * 33;
        const float* prow = B1 + e * SB1;
        float a0 = 0.f, a1 = 0.f, a2 = 0.f;
        matvec3_v<32>(wrow, prow, a0, a1, a2);
        const float w32 = wrow[32];
        a0 = fmaf(w32, prow[96], a0); a1 = fmaf(w32, prow[97], a1); a2 = fmaf(w32, prow[98], a2);
        const float nrm = sqrtf(fmaxf(a0 * a0 + a1 * a1 + a2 * a2, EPSF));
        const float sg = 1.f / (1.f + __expf(-nrm));
        float* p2 = B2 + e * SB2 + o * 3;
        p2[0] = a0 * sg; p2[1] = a1 * sg; p2[2] = a2 * sg;
    }
    __syncthreads();

    // E6: vh2 -> B1; vn2 -> PB[128,144); zero PB[144,160)
    #pragma unroll
    for (int it = 0; it < 2; ++it) {
        const int h = q8 + 8 * it;
        float a0 = 0.f, a1 = 0.f, a2 = 0.f;
        matvec3_v<16>(m2_wh + h * 16, B2 + e * SB2, a0, a1, a2);
        float* o = B1 + e * SB1 + h * 3;
        o[0] = a0; o[1] = a1; o[2] = a2;
        const float vn = sqrtf(fmaxf(a0 * a0 + a1 * a1 + a2 * a2, EPSF));
        unsigned short hh, ll; split_bf(vn, hh, ll);
        PBh[e * SBs + 128 + h] = hh; PBl[e * SBs + 128 + h] = ll;
        PBh[e * SBs + 144 + h] = 0;  PBl[e * SBs + 144 + h] = 0;
    }
    __syncthreads();

    // E8a: m2 MFMA (K=160)
    float4v acc2[8];
    #pragma unroll
    for (int i = 0; i < 8; ++i) acc2[i] = (float4v){0.f, 0.f, 0.f, 0.f};
    kloop<5, 8, SBs, 7>(PBh, PBl, p2h, p2l, acc2, lane, 0);
    __syncthreads();

    // E8b: relu -> A[m<8][0,128); vout2 -> B2
    {
        const int q = lane >> 4;
        #pragma unroll
        for (int i = 0; i < 8; ++i) {
            const int n = i * 16 + (lane & 15);
            const float bias = m2_wsb[n];
            #pragma unroll
            for (int r = 0; r < 4; ++r) {
                const int m = q * 4 + r;
                if (m < 8) {
                    const float x = fmaxf(acc2[i][r] + bias, 0.f);
                    unsigned short h, l; split_bf(x, h, l);
                    Ah[m * SA2 + n] = h; Al[m * SA2 + n] = l;
                }
            }
        }
    }
    __syncthreads();
    #pragma unroll
    for (int it = 0; it < 2; ++it) {
        const int o = q8 + 8 * it;
        float a0 = 0.f, a1 = 0.f, a2 = 0.f;
        matvec3_v<16>(m2_wv + o * 16, B1 + e * SB1, a0, a1, a2);
        const float nrm = sqrtf(fmaxf(a0 * a0 + a1 * a1 + a2 * a2, EPSF));
        const float sg = 1.f / (1.f + __expf(-nrm));
        float* p2 = B2 + e * SB2 + o * 3;
        p2[0] = a0 * sg; p2[1] = a1 * sg; p2[2] = a2 * sg;
    }
    __syncthreads();

    // E9: vh3 -> B1; vn3 -> A[128,144); zero A[144,160)
    #pragma unroll
    for (int it = 0; it < 2; ++it) {
        const int h = q8 + 8 * it;
        float a0 = 0.f, a1 = 0.f, a2 = 0.f;
        matvec3_v<16>(m3_wh + h * 16, B2 + e * SB2, a0, a1, a2);
        float* o = B1 + e * SB1 + h * 3;
        o[0] = a0; o[1] = a1; o[2] = a2;
        const float vn = sqrtf(fmaxf(a0 * a0 + a1 * a1 + a2 * a2, EPSF));
        unsigned short hh, ll; split_bf(vn, hh, ll);
        Ah[e * SA2 + 128 + h] = hh; Al[e * SA2 + 128 + h] = ll;
        Ah[e * SA2 + 144 + h] = 0;  Al[e * SA2 + 144 + h] = 0;
    }
    __syncthreads();

    // E11: m3 MFMA (K=160, no act); vout3 -> B2
    float4v acc3[8];
    #pragma unroll
    for (int i = 0; i < 8; ++i) acc3[i] = (float4v){0.f, 0.f, 0.f, 0.f};
    kloop<5, 8, SA2, 7>(Ah, Al, p3h, p3l, acc3, lane, 0);
    #pragma unroll
    for (int it = 0; it < 2; ++it) {
        const int o = q8 + 8 * it;
        float a0 = 0.f, a1 = 0.f, a2 = 0.f;
        matvec3_v<16>(m3_wv + o * 16, B1 + e * SB1, a0, a1, a2);
        float* p2 = B2 + e * SB2 + o * 3;
        p2[0] = a0; p2[1] = a1; p2[2] = a2;
    }
    __syncthreads();

    // E12: scatter-add (fp64 atomics -> order-invariant)
    {
        const int q = lane >> 4;
        #pragma unroll
        for (int i = 0; i < 8; ++i) {
            const int n = i * 16 + (lane & 15);
            const float bias = m3_wsb[n];
            #pragma unroll
            for (int r = 0; r < 4; ++r) {
                const int m = q * 4 + r;
                if (m < 8) {
                    const int d = sdst[m];
                    if (d >= 0) atomicAdd(&agg_s[(size_t)d * 128 + n], (double)(acc3[i][r] + bias));
                }
            }
        }
    }
    #pragma unroll
    for (int it = 0; it < 6; ++it) {
        const int j = q8 + 8 * it;     // j < 48 exactly
        const int d = sdst[e];
        if (d >= 0) atomicAdd(&agg_v[(size_t)d * 48 + j], (double)B2[e * SB2 + j]);
    }
    if (lane < 8 && sdst[lane] >= 0) atomicAdd(&cnt[sdst[lane]], 1.0f);
}

// ===========================================================================
// layer_normT: wave processes NE nodes (proven math, verbatim per node)
// ===========================================================================
template<int NE, int SSTR, int VSTR>
__device__ __forceinline__ void layer_normT(float* S, float* V,
    const float* __restrict__ g, const float* __restrict__ b, float* red, int lane)
{
    #pragma unroll
    for (int e = 0; e < NE; ++e) {
        float x0 = S[e * SSTR + lane], x1 = S[e * SSTR + 64 + lane];
        float sum = x0 + x1;
        #pragma unroll
        for (int off = 32; off > 0; off >>= 1) sum += __shfl_xor(sum, off, 64);
        const float mu = sum * (1.f / 128.f);
        const float d0 = x0 - mu, d1 = x1 - mu;
        float vs = d0 * d0 + d1 * d1;
        #pragma unroll
        for (int off = 32; off > 0; off >>= 1) vs += __shfl_xor(vs, off, 64);
        const float rstd = rsqrtf(vs * (1.f / 128.f) + 1e-5f);
        S[e * SSTR + lane]      = d0 * rstd * g[lane]      + b[lane];
        S[e * SSTR + 64 + lane] = d1 * rstd * g[lane + 64] + b[lane + 64];

        if (lane < 16) {
            const float a = V[e * VSTR + lane * 3], bb = V[e * VSTR + lane * 3 + 1],
                        cc = V[e * VSTR + lane * 3 + 2];
            const float vn = fmaxf(a * a + bb * bb + cc * cc, EPSF);
            red[lane]      = vn;
            red[16 + lane] = (vn > 2.f * EPSF) ? 1.f : 0.f;
        }
        __syncthreads();
        float sn = 0.f, sm = 0.f;
        #pragma unroll
        for (int i = 0; i < 16; ++i) { sn += red[i] * red[16 + i]; sm += red[16 + i]; }
        const float rvm = rsqrtf(sn / (EPSF + sm) + EPSF);
        if (lane < 48) V[e * VSTR + lane] = red[16 + lane / 3] * V[e * VSTR + lane] * rvm;
        __syncthreads();
    }
}

// ===========================================================================
// Node kernel (green in R10, verbatim): 8 nodes/block, 128 threads, 2 waves.
// f1 + f2 both via 3-pass split-bf16 MFMA (f2 uses MCLAMP=7).
// ===========================================================================
constexpr int NNS  = 132;
constexpr int NNV  = 52;
constexpr int NNH  = 100;
constexpr int NA1n = 168;
constexpr int NA2n = 552;   // f2 A stride (shorts), K=544

__global__ __launch_bounds__(128)
void node_kernel(const float* __restrict__ s, const float* __restrict__ v,
                 const float* __restrict__ f1_wh, const float* __restrict__ f1_wsb,
                 const float* __restrict__ f1_wv,
                 const float* __restrict__ f2_wh, const float* __restrict__ f2_wsb,
                 const float* __restrict__ f2_wv,
                 const float* __restrict__ ln0_g, const float* __restrict__ ln0_b,
                 const float* __restrict__ ln1_g, const float* __restrict__ ln1_b,
                 const unsigned short* __restrict__ pf1h, const unsigned short* __restrict__ pf1l,
                 const unsigned short* __restrict__ pf2h, const unsigned short* __restrict__ pf2l,
                 const double* __restrict__ agg_s, const double* __restrict__ agg_v,
                 const float* __restrict__ cnt,
                 float* __restrict__ out, int N)
{
    __shared__ __align__(16) unsigned short UBh[8 * NA1n], UBl[8 * NA1n];
    __shared__ __align__(16) unsigned short UB2h[8 * NA2n], UB2l[8 * NA2n];
    __shared__ __align__(16) float S1f[8 * NNS];
    __shared__ __align__(16) float V1f[8 * NNV];
    __shared__ __align__(16) float VH[8 * NNH];
    __shared__ __align__(16) float FV[8 * NNH];
    __shared__ float red[2 * 32];

    const int tid = threadIdx.x, lane = tid & 63, wave = tid >> 6;
    const int e = tid & 7, qq = tid >> 3;
    const int n0 = blockIdx.x * 8;

    bool oks[4];
    #pragma unroll
    for (int e4 = 0; e4 < 4; ++e4) {
        const int idx = wave * 4 + e4;
        const int ng = n0 + idx;
        oks[e4] = (ng < N);
        const int n = oks[e4] ? ng : (N - 1);
        const double inv = 1.0 / (double)fmaxf(cnt[n], 1.f);
        if (lane < 32) {
            const float4 a = ((const float4*)(s + (size_t)n * 128))[lane];
            const double2 b0 = ((const double2*)(agg_s + (size_t)n * 128))[2 * lane];
            const double2 b1 = ((const double2*)(agg_s + (size_t)n * 128))[2 * lane + 1];
            float4 r;
            r.x = (float)((double)a.x + b0.x * inv);
            r.y = (float)((double)a.y + b0.y * inv);
            r.z = (float)((double)a.z + b1.x * inv);
            r.w = (float)((double)a.w + b1.y * inv);
            ((float4*)(S1f + idx * NNS))[lane] = r;
        }
        if (lane < 12) {
            const float4 a = ((const float4*)(v + (size_t)n * 48))[lane];
            const double2 b0 = ((const double2*)(agg_v + (size_t)n * 48))[2 * lane];
            const double2 b1 = ((const double2*)(agg_v + (size_t)n * 48))[2 * lane + 1];
            float4 r;
            r.x = (float)((double)a.x + b0.x * inv);
            r.y = (float)((double)a.y + b0.y * inv);
            r.z = (float)((double)a.z + b1.x * inv);
            r.w = (float)((double)a.w + b1.y * inv);
            ((float4*)(V1f + idx * NNV))[lane] = r;
        }
    }
    __syncthreads();

    layer_normT<4, NNS, NNV>(S1f + wave * 4 * NNS, V1f + wave * 4 * NNV,
                             ln0_g, ln0_b, red + wave * 32, lane);

    {
        const float* sp = S1f + e * NNS + qq * 8;
        short8 hv, lv; unsigned short h, l;
        #pragma unroll
        for (int j = 0; j < 8; ++j) { split_bf(sp[j], h, l); hv[j] = h; lv[j] = l; }
        *(short8*)(UBh + e * NA1n + qq * 8) = hv;
        *(short8*)(UBl + e * NA1n + qq * 8) = lv;
    }
    #pragma unroll
    for (int hi = 0; hi < 2; ++hi) {
        const int h = qq + 16 * hi;
        float a0 = 0.f, a1 = 0.f, a2 = 0.f;
        matvec3_v<16>(f1_wh + h * 16, V1f + e * NNV, a0, a1, a2);
        float* o = VH + e * NNH + h * 3;
        o[0] = a0; o[1] = a1; o[2] = a2;
        const float vn = sqrtf(fmaxf(a0 * a0 + a1 * a1 + a2 * a2, EPSF));
        unsigned short hh, ll; split_bf(vn, hh, ll);
        UBh[e * NA1n + 128 + h] = hh; UBl[e * NA1n + 128 + h] = ll;
    }
    __syncthreads();

    {
        float4v acc1[16];
        #pragma unroll
        for (int i = 0; i < 16; ++i) acc1[i] = (float4v){0.f, 0.f, 0.f, 0.f};
        kloop<5, 16, NA1n>(UBh, UBl, pf1h, pf1l, acc1, lane, wave);
        const int q = lane >> 4;
        #pragma unroll
        for (int i = 0; i < 16; ++i) {
            const int n = (wave * 16 + i) * 16 + (lane & 15);
            const float bias = f1_wsb[n];
            #pragma unroll
            for (int r = 0; r < 4; ++r) {
                const int m = q * 4 + r;
                if (m < 8) {
                    const float x = fmaxf(acc1[i][r] + bias, 0.f);
                    unsigned short h, l; split_bf(x, h, l);
                    UB2h[m * NA2n + n] = h; UB2l[m * NA2n + n] = l;
                }
            }
        }
    }
    #pragma unroll
    for (int oi = 0; oi < 2; ++oi) {
        const int o = qq + 16 * oi;
        float a0 = 0.f, a1 = 0.f, a2 = 0.f;
        matvec3_v<32>(f1_wv + o * 32, VH + e * NNH, a0, a1, a2);
        const float nrm = sqrtf(fmaxf(a0 * a0 + a1 * a1 + a2 * a2, EPSF));
        const float sg = 1.f / (1.f + __expf(-nrm));
        float* p2 = FV + e * NNH + o * 3;
        p2[0] = a0 * sg; p2[1] = a1 * sg; p2[2] = a2 * sg;
    }
    __syncthreads();

    #pragma unroll
    for (int hi = 0; hi < 2; ++hi) {
        const int h = qq + 16 * hi;
        float a0 = 0.f, a1 = 0.f, a2 = 0.f;
        matvec3_v<32>(f2_wh + h * 32, FV + e * NNH, a0, a1, a2);
        float* o = VH + e * NNH + h * 3;
        o[0] = a0; o[1] = a1; o[2] = a2;
        const float vn = sqrtf(fmaxf(a0 * a0 + a1 * a1 + a2 * a2, EPSF));
        unsigned short hh, ll; split_bf(vn, hh, ll);
        UB2h[e * NA2n + 512 + h] = hh; UB2l[e * NA2n + 512 + h] = ll;
    }
    __syncthreads();

    {
        float4v acc2[4] = {{0,0,0,0},{0,0,0,0},{0,0,0,0},{0,0,0,0}};
        kloop<17, 4, NA2n, 7>(UB2h, UB2l, pf2h, pf2l, acc2, lane, wave);
        const int q = lane >> 4;
        #pragma unroll
        for (int i = 0; i < 4; ++i) {
            const int n = (wave * 4 + i) * 16 + (lane & 15);
            const float bias = f2_wsb[n];
            #pragma unroll
            for (int r = 0; r < 4; ++r) {
                const int m = q * 4 + r;
                if (m < 8) S1f[m * NNS + n] += acc2[i][r] + bias;
            }
        }
    }
    {
        const int o = qq;
        float a0 = 0.f, a1 = 0.f, a2 = 0.f;
        matvec3_v<32>(f2_wv + o * 32, VH + e * NNH, a0, a1, a2);
        float* p2 = V1f + e * NNV + o * 3;
        p2[0] += a0; p2[1] += a1; p2[2] += a2;
    }
    __syncthreads();

    layer_normT<4, NNS, NNV>(S1f + wave * 4 * NNS, V1f + wave * 4 * NNV,
                             ln1_g, ln1_b, red + wave * 32, lane);

    #pragma unroll
    for (int e4 = 0; e4 < 4; ++e4) {
        if (!oks[e4]) continue;
        const int idx = wave * 4 + e4;
        const int n = n0 + idx;
        if (lane < 32)
            ((float4*)(out + (size_t)n * 128))[lane] = ((const float4*)(S1f + idx * NNS))[lane];
        if (lane < 12)
            ((float4*)(out + (size_t)N * 128 + (size_t)n * 48))[lane] =
                ((const float4*)(V1f + idx * NNV))[lane];
    }
}

// ---------------------------------------------------------------------------
extern "C" void kernel_launch(void* const* d_in, const int* in_sizes, int n_in,
                              void* d_out, int out_size, void* d_ws, size_t ws_size,
                              hipStream_t stream)
{
    const float* s    = (const float*)d_in[0];
    const float* v    = (const float*)d_in[1];
    const int*   eidx = (const int*)d_in[2];
    const float* es   = (const float*)d_in[3];
    const float* ev   = (const float*)d_in[4];
    const float* m1_wh = (const float*)d_in[5];
    const float* m1_wsw = (const float*)d_in[6];
    const float* m1_wsb = (const float*)d_in[7];
    const float* m1_wv = (const float*)d_in[8];
    const float* m2_wh = (const float*)d_in[9];
    const float* m2_wsw = (const float*)d_in[10];
    const float* m2_wsb = (const float*)d_in[11];
    const float* m2_wv = (const float*)d_in[12];
    const float* m3_wh = (const float*)d_in[13];
    const float* m3_wsw = (const float*)d_in[14];
    const float* m3_wsb = (const float*)d_in[15];
    const float* m3_wv = (const float*)d_in[16];
    const float* f1_wh = (const float*)d_in[17];
    const float* f1_wsw = (const float*)d_in[18];
    const float* f1_wsb = (const float*)d_in[19];
    const float* f1_wv = (const float*)d_in[20];
    const float* f2_wh = (const float*)d_in[21];
    const float* f2_wsw = (const float*)d_in[22];
    const float* f2_wsb = (const float*)d_in[23];
    const float* f2_wv = (const float*)d_in[24];
    const float* ln0_g = (const float*)d_in[25];
    const float* ln0_b = (const float*)d_in[26];
    const float* ln1_g = (const float*)d_in[27];
    const float* ln1_b = (const float*)d_in[28];

    const int N = in_sizes[0] / 128;
    const int E = in_sizes[2] / 2;

    double* agg_s = (double*)d_ws;                     // N*128 f64
    double* agg_v = agg_s + (size_t)N * 128;           // N*48  f64
    float* cnt    = (float*)(agg_v + (size_t)N * 48);  // N     f32
    unsigned short* pk =
        (unsigned short*)(((uintptr_t)(cnt + N) + 15) & ~(uintptr_t)15);
    const int S_P1E = 12288, S_M23 = 20480, S_MN = 32768, S_F1 = 81920, S_F2 = 69632;
    unsigned short* p1h = pk;            unsigned short* p1l = p1h + S_P1E;
    unsigned short* p2h = p1l + S_P1E;   unsigned short* p2l = p2h + S_M23;
    unsigned short* p3h = p2l + S_M23;   unsigned short* p3l = p3h + S_M23;
    unsigned short* pnh = p3l + S_M23;   unsigned short* pnl = pnh + S_MN;
    unsigned short* pf1h = pnl + S_MN;   unsigned short* pf1l = pf1h + S_F1;
    unsigned short* pf2h = pf1l + S_F1;  unsigned short* pf2l = pf2h + S_F2;
    float* Pg  = (float*)(((uintptr_t)(pf2l + S_F2) + 15) & ~(uintptr_t)15);
    float* Q1g = Pg + (size_t)N * 256;
    float* Q3g = Q1g + (size_t)N * 100;

    hipMemsetAsync(d_ws, 0,
                   (size_t)N * 176 * sizeof(double) + (size_t)N * sizeof(float),
                   stream);

    pack_m1e<<<dim3((12288 + 255) / 256), dim3(256), 0, stream>>>(m1_wsw, p1h, p1l);
    pack_w<<<dim3((S_M23 + 255) / 256), dim3(256), 0, stream>>>(m2_wsw, p2h, p2l, 128, 144, 5);
    pack_w<<<dim3((S_M23 + 255) / 256), dim3(256), 0, stream>>>(m3_wsw, p3h, p3l, 128, 144, 5);
    pack_m1n<<<dim3((32768 + 255) / 256), dim3(256), 0, stream>>>(m1_wsw, pnh, pnl);
    pack_w<<<dim3((S_F1 + 255) / 256), dim3(256), 0, stream>>>(f1_wsw, pf1h, pf1l, 512, 160, 5);
    pack_w<<<dim3((S_F2 + 255) / 256), dim3(256), 0, stream>>>(f2_wsw, pf2h, pf2l, 128, 544, 17);

    node_pre<<<dim3((N + 15) / 16), dim3(256), 0, stream>>>(
        s, v, m1_wh, m1_wsb, pnh, pnl, Pg, Q1g, Q3g, N);

    edge_kernel<<<dim3((E + 7) / 8), dim3(64), 0, stream>>>(
        eidx, es, ev,
        m1_wh, m1_wv,
        m2_wh, m2_wsb, m2_wv,
        m3_wh, m3_wsb, m3_wv,
        p1h, p1l, p2h, p2l, p3h, p3l,
        Pg, Q1g, Q3g,
        agg_s, agg_v, cnt, E);

    node_kernel<<<dim3((N + 7) / 8), dim3(128), 0, stream>>>(
        s, v,
        f1_wh, f1_wsb, f1_wv,
        f2_wh, f2_wsb, f2_wv,
        ln0_g, ln0_b, ln1_g, ln1_b,
        pf1h, pf1l, pf2h, pf2l,
        agg_s, agg_v, cnt,
        (float*)d_out, N);
}

// Round 12
// 1169.435 us; speedup vs baseline: 1.6960x; 1.6960x over previous
//
#include <hip/hip_runtime.h>

#define EPSF 1e-8f
#define AGG_SCALE 1048576.f          // 2^20 fixed-point (Q11.20)
#define AGG_INV   (1.0 / 1048576.0)

typedef __attribute__((ext_vector_type(8))) short short8;
typedef __attribute__((ext_vector_type(4))) short short4v;
typedef __attribute__((ext_vector_type(4))) float float4v;

// ---- fp32 -> bf16 hi/lo split (RNE) ---------------------------------------
__device__ __forceinline__ unsigned bfhi_bits(float x) {
    unsigned u = __float_as_uint(x);
    return (u + 0x7fffu + ((u >> 16) & 1u)) >> 16;
}
__device__ __forceinline__ float bits2f(unsigned b) { return __uint_as_float(b << 16); }
__device__ __forceinline__ void split_bf(float x, unsigned short& h, unsigned short& l) {
    unsigned hb = bfhi_bits(x);
    h = (unsigned short)hb;
    l = (unsigned short)bfhi_bits(x - bits2f(hb));
}

// ---------------------------------------------------------------------------
// matvec3_v: acc[t] += sum_h wrow[h] * prow[h*3+t], NH entries (mult of 4),
// prow 16B-aligned LDS. float4 loads; per-accumulator fma order identical to
// the scalar h-loop (h strictly increasing) -> bit-identical results.
// ---------------------------------------------------------------------------
template<int NH>
__device__ __forceinline__ void matvec3_v(const float* __restrict__ wrow,
                                          const float* prow,
                                          float& a0, float& a1, float& a2)
{
    #pragma unroll
    for (int g = 0; g < NH / 4; ++g) {
        const float4 f0 = ((const float4*)prow)[3 * g + 0];
        const float4 f1 = ((const float4*)prow)[3 * g + 1];
        const float4 f2 = ((const float4*)prow)[3 * g + 2];
        const float w0 = wrow[4 * g + 0], w1 = wrow[4 * g + 1];
        const float w2 = wrow[4 * g + 2], w3 = wrow[4 * g + 3];
        a0 = fmaf(w0, f0.x, a0); a1 = fmaf(w0, f0.y, a1); a2 = fmaf(w0, f0.z, a2);
        a0 = fmaf(w1, f0.w, a0); a1 = fmaf(w1, f1.x, a1); a2 = fmaf(w1, f1.y, a2);
        a0 = fmaf(w2, f1.z, a0); a1 = fmaf(w2, f1.w, a1); a2 = fmaf(w2, f2.x, a2);
        a0 = fmaf(w3, f2.y, a0); a1 = fmaf(w3, f2.z, a1); a2 = fmaf(w3, f2.w, a2);
    }
}

// ---------------------------------------------------------------------------
// Pack W[NO][K] fp32 (row-major) into MFMA B-fragment order, bf16 hi/lo.
// ---------------------------------------------------------------------------
__global__ void pack_w(const float* __restrict__ W, unsigned short* __restrict__ hi,
                       unsigned short* __restrict__ lo, int NO, int K, int steps) {
    const int gid = blockIdx.x * 256 + threadIdx.x;
    const int total = (NO >> 4) * steps * 512;
    if (gid >= total) return;
    const int j = gid & 7, l = (gid >> 3) & 63, rest = gid >> 9;
    const int t = rest % steps, nt = rest / steps;
    const int n = nt * 16 + (l & 15);
    const int k = t * 32 + ((l >> 4) << 3) + j;
    const float x = (k < K) ? W[(size_t)n * K + k] : 0.f;
    unsigned short h, lw;
    split_bf(x, h, lw);
    hi[gid] = h; lo[gid] = lw;
}

// pack m1 edge-part B: NO=128, K=96, steps=3.
__global__ void pack_m1e(const float* __restrict__ W, unsigned short* __restrict__ hi,
                         unsigned short* __restrict__ lo) {
    const int gid = blockIdx.x * 256 + threadIdx.x;
    if (gid >= 12288) return;
    const int j = gid & 7, l = (gid >> 3) & 63, rest = gid >> 9;
    const int t = rest % 3, nt = rest / 3;
    const int n = nt * 16 + (l & 15);
    const int k = t * 32 + ((l >> 4) << 3) + j;
    float x = 0.f;
    if (k < 32)      x = W[(size_t)n * 321 + 128 + k];
    else if (k < 65) x = W[(size_t)n * 321 + 288 + (k - 32)];
    unsigned short h, lw; split_bf(x, h, lw);
    hi[gid] = h; lo[gid] = lw;
}

// pack node-pre B: NO=256, K=128, steps=4.
__global__ void pack_m1n(const float* __restrict__ W, unsigned short* __restrict__ hi,
                         unsigned short* __restrict__ lo) {
    const int gid = blockIdx.x * 256 + threadIdx.x;
    if (gid >= 32768) return;
    const int j = gid & 7, l = (gid >> 3) & 63, rest = gid >> 9;
    const int t = rest & 3, nt = rest >> 2;
    const int n = nt * 16 + (l & 15);
    const int k = t * 32 + ((l >> 4) << 3) + j;
    const float x = (n < 128) ? W[(size_t)n * 321 + k]
                              : W[(size_t)(n - 128) * 321 + 160 + k];
    unsigned short h, lw; split_bf(x, h, lw);
    hi[gid] = h; lo[gid] = lw;
}

// ---------------------------------------------------------------------------
// 3-pass split-bf16 MFMA K-loop (validated).  MCLAMP masks the A-row index.
// ---------------------------------------------------------------------------
template<int STEPS, int NTPW, int ASTR, int MCLAMP = 15>
__device__ __forceinline__ void kloop(const unsigned short* PAh, const unsigned short* PAl,
    const unsigned short* __restrict__ wph, const unsigned short* __restrict__ wpl,
    float4v* acc, int lane, int wave)
{
    const int m = (lane & 15) & MCLAMP, q = lane >> 4;
    for (int t = 0; t < STEPS; ++t) {
        const int k0 = t * 32 + q * 8;
        const short8 ah = *(const short8*)(PAh + m * ASTR + k0);
        const short8 al = *(const short8*)(PAl + m * ASTR + k0);
        #pragma unroll
        for (int i = 0; i < NTPW; ++i) {
            const int nt = wave * NTPW + i;
            const size_t off = ((size_t)(nt * STEPS + t) * 64 + lane) * 8;
            const short8 bh = *(const short8*)(wph + off);
            const short8 bl = *(const short8*)(wpl + off);
            acc[i] = __builtin_amdgcn_mfma_f32_16x16x32_bf16(ah, bh, acc[i], 0, 0, 0);
            acc[i] = __builtin_amdgcn_mfma_f32_16x16x32_bf16(al, bh, acc[i], 0, 0, 0);
            acc[i] = __builtin_amdgcn_mfma_f32_16x16x32_bf16(ah, bl, acc[i], 0, 0, 0);
        }
    }
}

// ===========================================================================
// node_pre (green in R5, verbatim)
// ===========================================================================
constexpr int PAS = 136;

__global__ __launch_bounds__(256)
void node_pre(const float* __restrict__ s, const float* __restrict__ v,
              const float* __restrict__ m1_wh, const float* __restrict__ m1_wsb,
              const unsigned short* __restrict__ pnh, const unsigned short* __restrict__ pnl,
              float* __restrict__ Pg, float* __restrict__ Q1g, float* __restrict__ Q3g,
              int N)
{
    __shared__ __align__(16) unsigned short Ah[16 * PAS], Al[16 * PAS];
    __shared__ __align__(16) float Vs[16 * 48];

    const int tid = threadIdx.x, lane = tid & 63, wave = tid >> 6;
    const int e = tid & 15, q16 = tid >> 4;
    const int n0 = blockIdx.x * 16;
    const int ne = min(n0 + e, N - 1);

    {
        const float* sp = s + (size_t)ne * 128 + q16 * 8;
        const float4 x = ((const float4*)sp)[0];
        const float4 y = ((const float4*)sp)[1];
        short8 hv, lv; unsigned short h, l;
        split_bf(x.x, h, l); hv[0] = h; lv[0] = l;
        split_bf(x.y, h, l); hv[1] = h; lv[1] = l;
        split_bf(x.z, h, l); hv[2] = h; lv[2] = l;
        split_bf(x.w, h, l); hv[3] = h; lv[3] = l;
        split_bf(y.x, h, l); hv[4] = h; lv[4] = l;
        split_bf(y.y, h, l); hv[5] = h; lv[5] = l;
        split_bf(y.z, h, l); hv[6] = h; lv[6] = l;
        split_bf(y.w, h, l); hv[7] = h; lv[7] = l;
        *(short8*)(Ah + e * PAS + q16 * 8) = hv;
        *(short8*)(Al + e * PAS + q16 * 8) = lv;
    }
    if (q16 < 12)
        ((float4*)(Vs + e * 48))[q16] = ((const float4*)(v + (size_t)ne * 48))[q16];
    __syncthreads();

    {
        float4v acc[4] = {{0,0,0,0},{0,0,0,0},{0,0,0,0},{0,0,0,0}};
        kloop<4, 4, PAS>(Ah, Al, pnh, pnl, acc, lane, wave);
        const int q = lane >> 4;
        #pragma unroll
        for (int i = 0; i < 4; ++i) {
            const int j = (wave * 4 + i) * 16 + (lane & 15);
            const float bias = (j < 128) ? m1_wsb[j] : 0.f;
            #pragma unroll
            for (int r = 0; r < 4; ++r) {
                const int m = q * 4 + r;
                if (n0 + m < N) Pg[(size_t)(n0 + m) * 256 + j] = acc[i][r] + bias;
            }
        }
    }
    #pragma unroll
    for (int k = 0; k < 7; ++k) {
        const int idx = tid + k * 256;
        if (idx < 16 * 99) {
            const int n = idx & 15, j = idx >> 4;
            const int h = j / 3, t = j - h * 3;
            const float* vb = Vs + n * 48 + t;
            const float* w = m1_wh + h * 33;
            float a1 = 0.f, a3 = 0.f;
            for (int c = 0; c < 16; ++c) {
                const float vv = vb[c * 3];
                a1 = fmaf(w[c], vv, a1);
                a3 = fmaf(w[17 + c], vv, a3);
            }
            const int nn = n0 + n;
            if (nn < N) {
                Q1g[(size_t)nn * 100 + j] = a1;
                Q3g[(size_t)nn * 100 + j] = a3;
            }
        }
    }
}

// ---------------------------------------------------------------------------
// Edge kernel (R10-green structure, 16 edges / 256 threads).  Only change:
// aggregation atomics are int32 fixed-point Q11.20 (exactly associative ->
// replay-deterministic; half the atomic bytes of fp64).
// ---------------------------------------------------------------------------
constexpr int SA2 = 168;
constexpr int SBs = 168;
constexpr int SB1 = 100;
constexpr int SB2 = 52;
constexpr int SPS = 132;

__global__ __launch_bounds__(256)
void edge_kernel(const int* __restrict__ eidx,
                 const float* __restrict__ es, const float* __restrict__ ev,
                 const float* __restrict__ m1_wh, const float* __restrict__ m1_wv,
                 const float* __restrict__ m2_wh, const float* __restrict__ m2_wsb,
                 const float* __restrict__ m2_wv,
                 const float* __restrict__ m3_wh, const float* __restrict__ m3_wsb,
                 const float* __restrict__ m3_wv,
                 const unsigned short* __restrict__ p1h, const unsigned short* __restrict__ p1l,
                 const unsigned short* __restrict__ p2h, const unsigned short* __restrict__ p2l,
                 const unsigned short* __restrict__ p3h, const unsigned short* __restrict__ p3l,
                 const float* __restrict__ Pg, const float* __restrict__ Q1g,
                 const float* __restrict__ Q3g,
                 int* __restrict__ agg_s, int* __restrict__ agg_v,
                 float* __restrict__ cnt, int E)
{
    __shared__ __align__(16) unsigned short Ah[16 * SA2], Al[16 * SA2];
    __shared__ __align__(16) float SP[16 * SPS];
    __shared__ __align__(16) float B1[16 * SB1];
    __shared__ int ssrc[16], sgd[16], sdst[16], seid[16];

    unsigned short* PBh = Ah;      // overlay: PB == A (identical geometry)
    unsigned short* PBl = Al;
    float* B2 = SP;                // overlay: B2 in SP's first 3328 B

    const int tid = threadIdx.x, lane = tid & 63, wave = tid >> 6;
    const int e = tid & 15, q16 = tid >> 4;
    const int e0 = blockIdx.x * 16;

    const int eg_r = e0 + e;
    const int ee_r = (eg_r < E) ? eg_r : (E - 1);
    const int src_r = eidx[ee_r];
    const int dst_r = eidx[E + ee_r];

    if (q16 < 8) {
        const float4 x = ((const float4*)(es + (size_t)ee_r * 32))[q16];
        short4v hv, lv; unsigned short h, l;
        split_bf(x.x, h, l); hv[0] = h; lv[0] = l;
        split_bf(x.y, h, l); hv[1] = h; lv[1] = l;
        split_bf(x.z, h, l); hv[2] = h; lv[2] = l;
        split_bf(x.w, h, l); hv[3] = h; lv[3] = l;
        *(short4v*)(Ah + e * SA2 + 4 * q16) = hv;
        *(short4v*)(Al + e * SA2 + 4 * q16) = lv;
    }
    { const int c = 65 + q16; Ah[e * SA2 + c] = 0; Al[e * SA2 + c] = 0; }
    { const int c = 81 + q16; if (c < 96) { Ah[e * SA2 + c] = 0; Al[e * SA2 + c] = 0; } }
    {
        const float* P1 = Pg + (size_t)src_r * 256;
        const float* P3 = Pg + (size_t)dst_r * 256 + 128;
        const float4 a0 = ((const float4*)P1)[2 * q16];
        const float4 a1 = ((const float4*)P1)[2 * q16 + 1];
        const float4 b0 = ((const float4*)P3)[2 * q16];
        const float4 b1 = ((const float4*)P3)[2 * q16 + 1];
        float4 r0, r1;
        r0.x = a0.x + b0.x; r0.y = a0.y + b0.y; r0.z = a0.z + b0.z; r0.w = a0.w + b0.w;
        r1.x = a1.x + b1.x; r1.y = a1.y + b1.y; r1.z = a1.z + b1.z; r1.w = a1.w + b1.w;
        float4* o = (float4*)(SP + e * SPS + 8 * q16);
        o[0] = r0; o[1] = r1;
    }
    if (tid < 16) {
        const int eg = e0 + tid;
        const bool ok = (eg < E);
        const int ee = ok ? eg : (E - 1);
        seid[tid] = ee;
        ssrc[tid] = eidx[ee];
        const int d = eidx[E + ee];
        sgd[tid] = d;
        sdst[tid] = ok ? d : -1;
    }
    __syncthreads();

    #pragma unroll
    for (int k = 0; k < 3; ++k) {
        const int idx = tid + k * 256;
        if (idx < 528) {
            const int h = idx >> 4, e2 = idx & 15;
            const float* q1 = Q1g + (size_t)ssrc[e2] * 100 + h * 3;
            const float* q3 = Q3g + (size_t)sgd[e2] * 100 + h * 3;
            const float* evp = ev + (size_t)seid[e2] * 3;
            const float w16 = m1_wh[h * 33 + 16];
            const float v0 = q1[0] + q3[0] + w16 * evp[0];
            const float v1 = q1[1] + q3[1] + w16 * evp[1];
            const float v2 = q1[2] + q3[2] + w16 * evp[2];
            float* o = B1 + e2 * SB1 + h * 3;
            o[0] = v0; o[1] = v1; o[2] = v2;
            const float vn = sqrtf(fmaxf(v0 * v0 + v1 * v1 + v2 * v2, EPSF));
            unsigned short hh, ll; split_bf(vn, hh, ll);
            Ah[e2 * SA2 + 32 + h] = hh; Al[e2 * SA2 + 32 + h] = ll;
        }
    }
    __syncthreads();

    float4v acc1[2] = {{0,0,0,0},{0,0,0,0}};
    kloop<3, 2, SA2>(Ah, Al, p1h, p1l, acc1, lane, wave);
    __syncthreads();

    {
        const int q = lane >> 4;
        #pragma unroll
        for (int i = 0; i < 2; ++i) {
            const int n = (wave * 2 + i) * 16 + (lane & 15);
            #pragma unroll
            for (int r = 0; r < 4; ++r) {
                const int m = q * 4 + r;
                const float x = fmaxf(acc1[i][r] + SP[m * SPS + n], 0.f);
                unsigned short h, l; split_bf(x, h, l);
                PBh[m * SBs + n] = h; PBl[m * SBs + n] = l;
            }
        }
    }
    __syncthreads();

    {
        const int o = q16;
        const float* wrow = m1_wv + o * 33;
        const float* prow = B1 + e * SB1;
        float a0 = 0.f, a1 = 0.f, a2 = 0.f;
        matvec3_v<32>(wrow, prow, a0, a1, a2);
        const float w32 = wrow[32];
        a0 = fmaf(w32, prow[96], a0); a1 = fmaf(w32, prow[97], a1); a2 = fmaf(w32, prow[98], a2);
        const float nrm = sqrtf(fmaxf(a0 * a0 + a1 * a1 + a2 * a2, EPSF));
        const float sg = 1.f / (1.f + __expf(-nrm));
        float* p2 = B2 + e * SB2 + o * 3;
        p2[0] = a0 * sg; p2[1] = a1 * sg; p2[2] = a2 * sg;
    }
    __syncthreads();

    {
        const int h = q16;
        float a0 = 0.f, a1 = 0.f, a2 = 0.f;
        matvec3_v<16>(m2_wh + h * 16, B2 + e * SB2, a0, a1, a2);
        float* o = B1 + e * SB1 + h * 3;
        o[0] = a0; o[1] = a1; o[2] = a2;
        const float vn = sqrtf(fmaxf(a0 * a0 + a1 * a1 + a2 * a2, EPSF));
        unsigned short hh, ll; split_bf(vn, hh, ll);
        PBh[e * SBs + 128 + h] = hh; PBl[e * SBs + 128 + h] = ll;
        PBh[e * SBs + 144 + h] = 0;  PBl[e * SBs + 144 + h] = 0;
    }
    __syncthreads();

    float4v acc2[2] = {{0,0,0,0},{0,0,0,0}};
    kloop<5, 2, SBs>(PBh, PBl, p2h, p2l, acc2, lane, wave);
    __syncthreads();

    {
        const int q = lane >> 4;
        #pragma unroll
        for (int i = 0; i < 2; ++i) {
            const int n = (wave * 2 + i) * 16 + (lane & 15);
            const float bias = m2_wsb[n];
            #pragma unroll
            for (int r = 0; r < 4; ++r) {
                const int m = q * 4 + r;
                const float x = fmaxf(acc2[i][r] + bias, 0.f);
                unsigned short h, l; split_bf(x, h, l);
                Ah[m * SA2 + n] = h; Al[m * SA2 + n] = l;
            }
        }
    }
    {
        const int o = q16;
        float a0 = 0.f, a1 = 0.f, a2 = 0.f;
        matvec3_v<16>(m2_wv + o * 16, B1 + e * SB1, a0, a1, a2);
        const float nrm = sqrtf(fmaxf(a0 * a0 + a1 * a1 + a2 * a2, EPSF));
        const float sg = 1.f / (1.f + __expf(-nrm));
        float* p2 = B2 + e * SB2 + o * 3;
        p2[0] = a0 * sg; p2[1] = a1 * sg; p2[2] = a2 * sg;
    }
    __syncthreads();

    {
        const int h = q16;
        float a0 = 0.f, a1 = 0.f, a2 = 0.f;
        matvec3_v<16>(m3_wh + h * 16, B2 + e * SB2, a0, a1, a2);
        float* o = B1 + e * SB1 + h * 3;
        o[0] = a0; o[1] = a1; o[2] = a2;
        const float vn = sqrtf(fmaxf(a0 * a0 + a1 * a1 + a2 * a2, EPSF));
        unsigned short hh, ll; split_bf(vn, hh, ll);
        Ah[e * SA2 + 128 + h] = hh; Al[e * SA2 + 128 + h] = ll;
        Ah[e * SA2 + 144 + h] = 0;  Al[e * SA2 + 144 + h] = 0;
    }
    __syncthreads();

    float4v acc3[2] = {{0,0,0,0},{0,0,0,0}};
    kloop<5, 2, SA2>(Ah, Al, p3h, p3l, acc3, lane, wave);
    {
        const int o = q16;
        float a0 = 0.f, a1 = 0.f, a2 = 0.f;
        matvec3_v<16>(m3_wv + o * 16, B1 + e * SB1, a0, a1, a2);
        float* p2 = B2 + e * SB2 + o * 3;
        p2[0] = a0; p2[1] = a1; p2[2] = a2;
    }
    __syncthreads();

    // E12: scatter-add (int32 fixed-point atomics -> exact, order-invariant)
    {
        const int q = lane >> 4;
        #pragma unroll
        for (int i = 0; i < 2; ++i) {
            const int n = (wave * 2 + i) * 16 + (lane & 15);
            const float bias = m3_wsb[n];
            #pragma unroll
            for (int r = 0; r < 4; ++r) {
                const int m = q * 4 + r;
                const int d = sdst[m];
                if (d >= 0)
                    atomicAdd(&agg_s[(size_t)d * 128 + n],
                              __float2int_rn((acc3[i][r] + bias) * AGG_SCALE));
            }
        }
    }
    #pragma unroll
    for (int it = 0; it < 3; ++it) {
        const int j = q16 + 16 * it;
        const int d = sdst[e];
        if (d >= 0)
            atomicAdd(&agg_v[(size_t)d * 48 + j],
                      __float2int_rn(B2[e * SB2 + j] * AGG_SCALE));
    }
    if (tid < 16 && sdst[tid] >= 0) atomicAdd(&cnt[sdst[tid]], 1.0f);
}

// ===========================================================================
// layer_normT: wave processes NE nodes (proven math, verbatim per node)
// ===========================================================================
template<int NE, int SSTR, int VSTR>
__device__ __forceinline__ void layer_normT(float* S, float* V,
    const float* __restrict__ g, const float* __restrict__ b, float* red, int lane)
{
    #pragma unroll
    for (int e = 0; e < NE; ++e) {
        float x0 = S[e * SSTR + lane], x1 = S[e * SSTR + 64 + lane];
        float sum = x0 + x1;
        #pragma unroll
        for (int off = 32; off > 0; off >>= 1) sum += __shfl_xor(sum, off, 64);
        const float mu = sum * (1.f / 128.f);
        const float d0 = x0 - mu, d1 = x1 - mu;
        float vs = d0 * d0 + d1 * d1;
        #pragma unroll
        for (int off = 32; off > 0; off >>= 1) vs += __shfl_xor(vs, off, 64);
        const float rstd = rsqrtf(vs * (1.f / 128.f) + 1e-5f);
        S[e * SSTR + lane]      = d0 * rstd * g[lane]      + b[lane];
        S[e * SSTR + 64 + lane] = d1 * rstd * g[lane + 64] + b[lane + 64];

        if (lane < 16) {
            const float a = V[e * VSTR + lane * 3], bb = V[e * VSTR + lane * 3 + 1],
                        cc = V[e * VSTR + lane * 3 + 2];
            const float vn = fmaxf(a * a + bb * bb + cc * cc, EPSF);
            red[lane]      = vn;
            red[16 + lane] = (vn > 2.f * EPSF) ? 1.f : 0.f;
        }
        __syncthreads();
        float sn = 0.f, sm = 0.f;
        #pragma unroll
        for (int i = 0; i < 16; ++i) { sn += red[i] * red[16 + i]; sm += red[16 + i]; }
        const float rvm = rsqrtf(sn / (EPSF + sm) + EPSF);
        if (lane < 48) V[e * VSTR + lane] = red[16 + lane / 3] * V[e * VSTR + lane] * rvm;
        __syncthreads();
    }
}

// ===========================================================================
// Node kernel (R10-green structure): 8 nodes/block, 128 threads, 2 waves.
// f1 + f2 both via 3-pass split-bf16 MFMA (f2 uses MCLAMP=7).  Only change:
// P0 reads int32 fixed-point agg (exact conversion in double).
// ===========================================================================
constexpr int NNS  = 132;
constexpr int NNV  = 52;
constexpr int NNH  = 100;
constexpr int NA1n = 168;
constexpr int NA2n = 552;   // f2 A stride (shorts), K=544

__global__ __launch_bounds__(128)
void node_kernel(const float* __restrict__ s, const float* __restrict__ v,
                 const float* __restrict__ f1_wh, const float* __restrict__ f1_wsb,
                 const float* __restrict__ f1_wv,
                 const float* __restrict__ f2_wh, const float* __restrict__ f2_wsb,
                 const float* __restrict__ f2_wv,
                 const float* __restrict__ ln0_g, const float* __restrict__ ln0_b,
                 const float* __restrict__ ln1_g, const float* __restrict__ ln1_b,
                 const unsigned short* __restrict__ pf1h, const unsigned short* __restrict__ pf1l,
                 const unsigned short* __restrict__ pf2h, const unsigned short* __restrict__ pf2l,
                 const int* __restrict__ agg_s, const int* __restrict__ agg_v,
                 const float* __restrict__ cnt,
                 float* __restrict__ out, int N)
{
    __shared__ __align__(16) unsigned short UBh[8 * NA1n], UBl[8 * NA1n];
    __shared__ __align__(16) unsigned short UB2h[8 * NA2n], UB2l[8 * NA2n];
    __shared__ __align__(16) float S1f[8 * NNS];
    __shared__ __align__(16) float V1f[8 * NNV];
    __shared__ __align__(16) float VH[8 * NNH];
    __shared__ __align__(16) float FV[8 * NNH];
    __shared__ float red[2 * 32];

    const int tid = threadIdx.x, lane = tid & 63, wave = tid >> 6;
    const int e = tid & 7, qq = tid >> 3;
    const int n0 = blockIdx.x * 8;

    bool oks[4];
    #pragma unroll
    for (int e4 = 0; e4 < 4; ++e4) {
        const int idx = wave * 4 + e4;
        const int ng = n0 + idx;
        oks[e4] = (ng < N);
        const int n = oks[e4] ? ng : (N - 1);
        const double inv = (1.0 / (double)fmaxf(cnt[n], 1.f)) * AGG_INV;
        if (lane < 32) {
            const float4 a = ((const float4*)(s + (size_t)n * 128))[lane];
            const int4 b = ((const int4*)(agg_s + (size_t)n * 128))[lane];
            float4 r;
            r.x = (float)((double)a.x + (double)b.x * inv);
            r.y = (float)((double)a.y + (double)b.y * inv);
            r.z = (float)((double)a.z + (double)b.z * inv);
            r.w = (float)((double)a.w + (double)b.w * inv);
            ((float4*)(S1f + idx * NNS))[lane] = r;
        }
        if (lane < 12) {
            const float4 a = ((const float4*)(v + (size_t)n * 48))[lane];
            const int4 b = ((const int4*)(agg_v + (size_t)n * 48))[lane];
            float4 r;
            r.x = (float)((double)a.x + (double)b.x * inv);
            r.y = (float)((double)a.y + (double)b.y * inv);
            r.z = (float)((double)a.z + (double)b.z * inv);
            r.w = (float)((double)a.w + (double)b.w * inv);
            ((float4*)(V1f + idx * NNV))[lane] = r;
        }
    }
    __syncthreads();

    layer_normT<4, NNS, NNV>(S1f + wave * 4 * NNS, V1f + wave * 4 * NNV,
                             ln0_g, ln0_b, red + wave * 32, lane);

    {
        const float* sp = S1f + e * NNS + qq * 8;
        short8 hv, lv; unsigned short h, l;
        #pragma unroll
        for (int j = 0; j < 8; ++j) { split_bf(sp[j], h, l); hv[j] = h; lv[j] = l; }
        *(short8*)(UBh + e * NA1n + qq * 8) = hv;
        *(short8*)(UBl + e * NA1n + qq * 8) = lv;
    }
    #pragma unroll
    for (int hi = 0; hi < 2; ++hi) {
        const int h = qq + 16 * hi;
        float a0 = 0.f, a1 = 0.f, a2 = 0.f;
        matvec3_v<16>(f1_wh + h * 16, V1f + e * NNV, a0, a1, a2);
        float* o = VH + e * NNH + h * 3;
        o[0] = a0; o[1] = a1; o[2] = a2;
        const float vn = sqrtf(fmaxf(a0 * a0 + a1 * a1 + a2 * a2, EPSF));
        unsigned short hh, ll; split_bf(vn, hh, ll);
        UBh[e * NA1n + 128 + h] = hh; UBl[e * NA1n + 128 + h] = ll;
    }
    __syncthreads();

    {
        float4v acc1[16];
        #pragma unroll
        for (int i = 0; i < 16; ++i) acc1[i] = (float4v){0.f, 0.f, 0.f, 0.f};
        kloop<5, 16, NA1n>(UBh, UBl, pf1h, pf1l, acc1, lane, wave);
        const int q = lane >> 4;
        #pragma unroll
        for (int i = 0; i < 16; ++i) {
            const int n = (wave * 16 + i) * 16 + (lane & 15);
            const float bias = f1_wsb[n];
            #pragma unroll
            for (int r = 0; r < 4; ++r) {
                const int m = q * 4 + r;
                if (m < 8) {
                    const float x = fmaxf(acc1[i][r] + bias, 0.f);
                    unsigned short h, l; split_bf(x, h, l);
                    UB2h[m * NA2n + n] = h; UB2l[m * NA2n + n] = l;
                }
            }
        }
    }
    #pragma unroll
    for (int oi = 0; oi < 2; ++oi) {
        const int o = qq + 16 * oi;
        float a0 = 0.f, a1 = 0.f, a2 = 0.f;
        matvec3_v<32>(f1_wv + o * 32, VH + e * NNH, a0, a1, a2);
        const float nrm = sqrtf(fmaxf(a0 * a0 + a1 * a1 + a2 * a2, EPSF));
        const float sg = 1.f / (1.f + __expf(-nrm));
        float* p2 = FV + e * NNH + o * 3;
        p2[0] = a0 * sg; p2[1] = a1 * sg; p2[2] = a2 * sg;
    }
    __syncthreads();

    #pragma unroll
    for (int hi = 0; hi < 2; ++hi) {
        const int h = qq + 16 * hi;
        float a0 = 0.f, a1 = 0.f, a2 = 0.f;
        matvec3_v<32>(f2_wh + h * 32, FV + e * NNH, a0, a1, a2);
        float* o = VH + e * NNH + h * 3;
        o[0] = a0; o[1] = a1; o[2] = a2;
        const float vn = sqrtf(fmaxf(a0 * a0 + a1 * a1 + a2 * a2, EPSF));
        unsigned short hh, ll; split_bf(vn, hh, ll);
        UB2h[e * NA2n + 512 + h] = hh; UB2l[e * NA2n + 512 + h] = ll;
    }
    __syncthreads();

    {
        float4v acc2[4] = {{0,0,0,0},{0,0,0,0},{0,0,0,0},{0,0,0,0}};
        kloop<17, 4, NA2n, 7>(UB2h, UB2l, pf2h, pf2l, acc2, lane, wave);
        const int q = lane >> 4;
        #pragma unroll
        for (int i = 0; i < 4; ++i) {
            const int n = (wave * 4 + i) * 16 + (lane & 15);
            const float bias = f2_wsb[n];
            #pragma unroll
            for (int r = 0; r < 4; ++r) {
                const int m = q * 4 + r;
                if (m < 8) S1f[m * NNS + n] += acc2[i][r] + bias;
            }
        }
    }
    {
        const int o = qq;
        float a0 = 0.f, a1 = 0.f, a2 = 0.f;
        matvec3_v<32>(f2_wv + o * 32, VH + e * NNH, a0, a1, a2);
        float* p2 = V1f + e * NNV + o * 3;
        p2[0] += a0; p2[1] += a1; p2[2] += a2;
    }
    __syncthreads();

    layer_normT<4, NNS, NNV>(S1f + wave * 4 * NNS, V1f + wave * 4 * NNV,
                             ln1_g, ln1_b, red + wave * 32, lane);

    #pragma unroll
    for (int e4 = 0; e4 < 4; ++e4) {
        if (!oks[e4]) continue;
        const int idx = wave * 4 + e4;
        const int n = n0 + idx;
        if (lane < 32)
            ((float4*)(out + (size_t)n * 128))[lane] = ((const float4*)(S1f + idx * NNS))[lane];
        if (lane < 12)
            ((float4*)(out + (size_t)N * 128 + (size_t)n * 48))[lane] =
                ((const float4*)(V1f + idx * NNV))[lane];
    }
}

// ---------------------------------------------------------------------------
extern "C" void kernel_launch(void* const* d_in, const int* in_sizes, int n_in,
                              void* d_out, int out_size, void* d_ws, size_t ws_size,
                              hipStream_t stream)
{
    const float* s    = (const float*)d_in[0];
    const float* v    = (const float*)d_in[1];
    const int*   eidx = (const int*)d_in[2];
    const float* es   = (const float*)d_in[3];
    const float* ev   = (const float*)d_in[4];
    const float* m1_wh = (const float*)d_in[5];
    const float* m1_wsw = (const float*)d_in[6];
    const float* m1_wsb = (const float*)d_in[7];
    const float* m1_wv = (const float*)d_in[8];
    const float* m2_wh = (const float*)d_in[9];
    const float* m2_wsw = (const float*)d_in[10];
    const float* m2_wsb = (const float*)d_in[11];
    const float* m2_wv = (const float*)d_in[12];
    const float* m3_wh = (const float*)d_in[13];
    const float* m3_wsw = (const float*)d_in[14];
    const float* m3_wsb = (const float*)d_in[15];
    const float* m3_wv = (const float*)d_in[16];
    const float* f1_wh = (const float*)d_in[17];
    const float* f1_wsw = (const float*)d_in[18];
    const float* f1_wsb = (const float*)d_in[19];
    const float* f1_wv = (const float*)d_in[20];
    const float* f2_wh = (const float*)d_in[21];
    const float* f2_wsw = (const float*)d_in[22];
    const float* f2_wsb = (const float*)d_in[23];
    const float* f2_wv = (const float*)d_in[24];
    const float* ln0_g = (const float*)d_in[25];
    const float* ln0_b = (const float*)d_in[26];
    const float* ln1_g = (const float*)d_in[27];
    const float* ln1_b = (const float*)d_in[28];

    const int N = in_sizes[0] / 128;
    const int E = in_sizes[2] / 2;

    int* agg_s = (int*)d_ws;                           // N*128 i32 (Q11.20)
    int* agg_v = agg_s + (size_t)N * 128;              // N*48  i32
    float* cnt = (float*)(agg_v + (size_t)N * 48);     // N     f32
    unsigned short* pk =
        (unsigned short*)(((uintptr_t)(cnt + N) + 15) & ~(uintptr_t)15);
    const int S_P1E = 12288, S_M23 = 20480, S_MN = 32768, S_F1 = 81920, S_F2 = 69632;
    unsigned short* p1h = pk;            unsigned short* p1l = p1h + S_P1E;
    unsigned short* p2h = p1l + S_P1E;   unsigned short* p2l = p2h + S_M23;
    unsigned short* p3h = p2l + S_M23;   unsigned short* p3l = p3h + S_M23;
    unsigned short* pnh = p3l + S_M23;   unsigned short* pnl = pnh + S_MN;
    unsigned short* pf1h = pnl + S_MN;   unsigned short* pf1l = pf1h + S_F1;
    unsigned short* pf2h = pf1l + S_F1;  unsigned short* pf2l = pf2h + S_F2;
    float* Pg  = (float*)(((uintptr_t)(pf2l + S_F2) + 15) & ~(uintptr_t)15);
    float* Q1g = Pg + (size_t)N * 256;
    float* Q3g = Q1g + (size_t)N * 100;

    hipMemsetAsync(d_ws, 0, (size_t)N * 177 * sizeof(int), stream);

    pack_m1e<<<dim3((12288 + 255) / 256), dim3(256), 0, stream>>>(m1_wsw, p1h, p1l);
    pack_w<<<dim3((S_M23 + 255) / 256), dim3(256), 0, stream>>>(m2_wsw, p2h, p2l, 128, 144, 5);
    pack_w<<<dim3((S_M23 + 255) / 256), dim3(256), 0, stream>>>(m3_wsw, p3h, p3l, 128, 144, 5);
    pack_m1n<<<dim3((32768 + 255) / 256), dim3(256), 0, stream>>>(m1_wsw, pnh, pnl);
    pack_w<<<dim3((S_F1 + 255) / 256), dim3(256), 0, stream>>>(f1_wsw, pf1h, pf1l, 512, 160, 5);
    pack_w<<<dim3((S_F2 + 255) / 256), dim3(256), 0, stream>>>(f2_wsw, pf2h, pf2l, 128, 544, 17);

    node_pre<<<dim3((N + 15) / 16), dim3(256), 0, stream>>>(
        s, v, m1_wh, m1_wsb, pnh, pnl, Pg, Q1g, Q3g, N);

    edge_kernel<<<dim3((E + 15) / 16), dim3(256), 0, stream>>>(
        eidx, es, ev,
        m1_wh, m1_wv,
        m2_wh, m2_wsb, m2_wv,
        m3_wh, m3_wsb, m3_wv,
        p1h, p1l, p2h, p2l, p3h, p3l,
        Pg, Q1g, Q3g,
        agg_s, agg_v, cnt, E);

    node_kernel<<<dim3((N + 7) / 8), dim3(128), 0, stream>>>(
        s, v,
        f1_wh, f1_wsb, f1_wv,
        f2_wh, f2_wsb, f2_wv,
        ln0_g, ln0_b, ln1_g, ln1_b,
        pf1h, pf1l, pf2h, pf2l,
        agg_s, agg_v, cnt,
        (float*)d_out, N);
}

// Round 13
// 1156.435 us; speedup vs baseline: 1.7150x; 1.0112x over previous
//
#include <hip/hip_runtime.h>

#define EPSF 1e-8f
#define AGG_SCALE 1048576.f          // 2^20 fixed-point (Q11.20)
#define AGG_INV   (1.0 / 1048576.0)

typedef __attribute__((ext_vector_type(8))) short short8;
typedef __attribute__((ext_vector_type(4))) short short4v;
typedef __attribute__((ext_vector_type(4))) float float4v;

// ---- fp32 -> bf16 hi/lo split (RNE) ---------------------------------------
__device__ __forceinline__ unsigned bfhi_bits(float x) {
    unsigned u = __float_as_uint(x);
    return (u + 0x7fffu + ((u >> 16) & 1u)) >> 16;
}
__device__ __forceinline__ float bits2f(unsigned b) { return __uint_as_float(b << 16); }
__device__ __forceinline__ void split_bf(float x, unsigned short& h, unsigned short& l) {
    unsigned hb = bfhi_bits(x);
    h = (unsigned short)hb;
    l = (unsigned short)bfhi_bits(x - bits2f(hb));
}

// ---------------------------------------------------------------------------
// matvec3_v: acc[t] += sum_h wrow[h] * prow[h*3+t], NH entries (mult of 4),
// prow 16B-aligned LDS. float4 loads; fma order identical to scalar h-loop.
// ---------------------------------------------------------------------------
template<int NH>
__device__ __forceinline__ void matvec3_v(const float* __restrict__ wrow,
                                          const float* prow,
                                          float& a0, float& a1, float& a2)
{
    #pragma unroll
    for (int g = 0; g < NH / 4; ++g) {
        const float4 f0 = ((const float4*)prow)[3 * g + 0];
        const float4 f1 = ((const float4*)prow)[3 * g + 1];
        const float4 f2 = ((const float4*)prow)[3 * g + 2];
        const float w0 = wrow[4 * g + 0], w1 = wrow[4 * g + 1];
        const float w2 = wrow[4 * g + 2], w3 = wrow[4 * g + 3];
        a0 = fmaf(w0, f0.x, a0); a1 = fmaf(w0, f0.y, a1); a2 = fmaf(w0, f0.z, a2);
        a0 = fmaf(w1, f0.w, a0); a1 = fmaf(w1, f1.x, a1); a2 = fmaf(w1, f1.y, a2);
        a0 = fmaf(w2, f1.z, a0); a1 = fmaf(w2, f1.w, a1); a2 = fmaf(w2, f2.x, a2);
        a0 = fmaf(w3, f2.y, a0); a1 = fmaf(w3, f2.z, a1); a2 = fmaf(w3, f2.w, a2);
    }
}

// ---------------------------------------------------------------------------
// Pack W[NO][K] fp32 (row-major) into MFMA B-fragment order, bf16 hi/lo.
// ---------------------------------------------------------------------------
__global__ void pack_w(const float* __restrict__ W, unsigned short* __restrict__ hi,
                       unsigned short* __restrict__ lo, int NO, int K, int steps) {
    const int gid = blockIdx.x * 256 + threadIdx.x;
    const int total = (NO >> 4) * steps * 512;
    if (gid >= total) return;
    const int j = gid & 7, l = (gid >> 3) & 63, rest = gid >> 9;
    const int t = rest % steps, nt = rest / steps;
    const int n = nt * 16 + (l & 15);
    const int k = t * 32 + ((l >> 4) << 3) + j;
    const float x = (k < K) ? W[(size_t)n * K + k] : 0.f;
    unsigned short h, lw;
    split_bf(x, h, lw);
    hi[gid] = h; lo[gid] = lw;
}

// pack m1 edge-part B: NO=128, K=96, steps=3.
__global__ void pack_m1e(const float* __restrict__ W, unsigned short* __restrict__ hi,
                         unsigned short* __restrict__ lo) {
    const int gid = blockIdx.x * 256 + threadIdx.x;
    if (gid >= 12288) return;
    const int j = gid & 7, l = (gid >> 3) & 63, rest = gid >> 9;
    const int t = rest % 3, nt = rest / 3;
    const int n = nt * 16 + (l & 15);
    const int k = t * 32 + ((l >> 4) << 3) + j;
    float x = 0.f;
    if (k < 32)      x = W[(size_t)n * 321 + 128 + k];
    else if (k < 65) x = W[(size_t)n * 321 + 288 + (k - 32)];
    unsigned short h, lw; split_bf(x, h, lw);
    hi[gid] = h; lo[gid] = lw;
}

// pack node-pre B: NO=256, K=128, steps=4.
__global__ void pack_m1n(const float* __restrict__ W, unsigned short* __restrict__ hi,
                         unsigned short* __restrict__ lo) {
    const int gid = blockIdx.x * 256 + threadIdx.x;
    if (gid >= 32768) return;
    const int j = gid & 7, l = (gid >> 3) & 63, rest = gid >> 9;
    const int t = rest & 3, nt = rest >> 2;
    const int n = nt * 16 + (l & 15);
    const int k = t * 32 + ((l >> 4) << 3) + j;
    const float x = (n < 128) ? W[(size_t)n * 321 + k]
                              : W[(size_t)(n - 128) * 321 + 160 + k];
    unsigned short h, lw; split_bf(x, h, lw);
    hi[gid] = h; lo[gid] = lw;
}

// ---------------------------------------------------------------------------
// 3-pass split-bf16 MFMA K-loop (validated).  MCLAMP masks the A-row index.
// ---------------------------------------------------------------------------
template<int STEPS, int NTPW, int ASTR, int MCLAMP = 15>
__device__ __forceinline__ void kloop(const unsigned short* PAh, const unsigned short* PAl,
    const unsigned short* __restrict__ wph, const unsigned short* __restrict__ wpl,
    float4v* acc, int lane, int wave)
{
    const int m = (lane & 15) & MCLAMP, q = lane >> 4;
    for (int t = 0; t < STEPS; ++t) {
        const int k0 = t * 32 + q * 8;
        const short8 ah = *(const short8*)(PAh + m * ASTR + k0);
        const short8 al = *(const short8*)(PAl + m * ASTR + k0);
        #pragma unroll
        for (int i = 0; i < NTPW; ++i) {
            const int nt = wave * NTPW + i;
            const size_t off = ((size_t)(nt * STEPS + t) * 64 + lane) * 8;
            const short8 bh = *(const short8*)(wph + off);
            const short8 bl = *(const short8*)(wpl + off);
            acc[i] = __builtin_amdgcn_mfma_f32_16x16x32_bf16(ah, bh, acc[i], 0, 0, 0);
            acc[i] = __builtin_amdgcn_mfma_f32_16x16x32_bf16(al, bh, acc[i], 0, 0, 0);
            acc[i] = __builtin_amdgcn_mfma_f32_16x16x32_bf16(ah, bl, acc[i], 0, 0, 0);
        }
    }
}

// ===========================================================================
// node_pre: R5-green structure; P and Q now stored as bf16 (halves the
// edge-kernel's random-gather traffic).
// ===========================================================================
constexpr int PAS = 136;

__global__ __launch_bounds__(256)
void node_pre(const float* __restrict__ s, const float* __restrict__ v,
              const float* __restrict__ m1_wh, const float* __restrict__ m1_wsb,
              const unsigned short* __restrict__ pnh, const unsigned short* __restrict__ pnl,
              unsigned short* __restrict__ Pgb, unsigned short* __restrict__ Q1b,
              unsigned short* __restrict__ Q3b, int N)
{
    __shared__ __align__(16) unsigned short Ah[16 * PAS], Al[16 * PAS];
    __shared__ __align__(16) float Vs[16 * 48];

    const int tid = threadIdx.x, lane = tid & 63, wave = tid >> 6;
    const int e = tid & 15, q16 = tid >> 4;
    const int n0 = blockIdx.x * 16;
    const int ne = min(n0 + e, N - 1);

    {
        const float* sp = s + (size_t)ne * 128 + q16 * 8;
        const float4 x = ((const float4*)sp)[0];
        const float4 y = ((const float4*)sp)[1];
        short8 hv, lv; unsigned short h, l;
        split_bf(x.x, h, l); hv[0] = h; lv[0] = l;
        split_bf(x.y, h, l); hv[1] = h; lv[1] = l;
        split_bf(x.z, h, l); hv[2] = h; lv[2] = l;
        split_bf(x.w, h, l); hv[3] = h; lv[3] = l;
        split_bf(y.x, h, l); hv[4] = h; lv[4] = l;
        split_bf(y.y, h, l); hv[5] = h; lv[5] = l;
        split_bf(y.z, h, l); hv[6] = h; lv[6] = l;
        split_bf(y.w, h, l); hv[7] = h; lv[7] = l;
        *(short8*)(Ah + e * PAS + q16 * 8) = hv;
        *(short8*)(Al + e * PAS + q16 * 8) = lv;
    }
    if (q16 < 12)
        ((float4*)(Vs + e * 48))[q16] = ((const float4*)(v + (size_t)ne * 48))[q16];
    __syncthreads();

    {
        float4v acc[4] = {{0,0,0,0},{0,0,0,0},{0,0,0,0},{0,0,0,0}};
        kloop<4, 4, PAS>(Ah, Al, pnh, pnl, acc, lane, wave);
        const int q = lane >> 4;
        #pragma unroll
        for (int i = 0; i < 4; ++i) {
            const int j = (wave * 4 + i) * 16 + (lane & 15);
            const float bias = (j < 128) ? m1_wsb[j] : 0.f;
            #pragma unroll
            for (int r = 0; r < 4; ++r) {
                const int m = q * 4 + r;
                if (n0 + m < N)
                    Pgb[(size_t)(n0 + m) * 256 + j] =
                        (unsigned short)bfhi_bits(acc[i][r] + bias);
            }
        }
    }
    #pragma unroll
    for (int k = 0; k < 7; ++k) {
        const int idx = tid + k * 256;
        if (idx < 16 * 99) {
            const int n = idx & 15, j = idx >> 4;
            const int h = j / 3, t = j - h * 3;
            const float* vb = Vs + n * 48 + t;
            const float* w = m1_wh + h * 33;
            float a1 = 0.f, a3 = 0.f;
            for (int c = 0; c < 16; ++c) {
                const float vv = vb[c * 3];
                a1 = fmaf(w[c], vv, a1);
                a3 = fmaf(w[17 + c], vv, a3);
            }
            const int nn = n0 + n;
            if (nn < N) {
                Q1b[(size_t)nn * 100 + j] = (unsigned short)bfhi_bits(a1);
                Q3b[(size_t)nn * 100 + j] = (unsigned short)bfhi_bits(a3);
            }
        }
    }
}

// ---------------------------------------------------------------------------
// Edge kernel (R12-green structure, 16 edges / 256 threads).  P/Q gathers
// now bf16 (half the bytes, half the cache lines per random gather).
// int32 fixed-point atomics (exact, order-invariant).
// ---------------------------------------------------------------------------
constexpr int SA2 = 168;
constexpr int SBs = 168;
constexpr int SB1 = 100;
constexpr int SB2 = 52;
constexpr int SPS = 132;

__global__ __launch_bounds__(256)
void edge_kernel(const int* __restrict__ eidx,
                 const float* __restrict__ es, const float* __restrict__ ev,
                 const float* __restrict__ m1_wh, const float* __restrict__ m1_wv,
                 const float* __restrict__ m2_wh, const float* __restrict__ m2_wsb,
                 const float* __restrict__ m2_wv,
                 const float* __restrict__ m3_wh, const float* __restrict__ m3_wsb,
                 const float* __restrict__ m3_wv,
                 const unsigned short* __restrict__ p1h, const unsigned short* __restrict__ p1l,
                 const unsigned short* __restrict__ p2h, const unsigned short* __restrict__ p2l,
                 const unsigned short* __restrict__ p3h, const unsigned short* __restrict__ p3l,
                 const unsigned short* __restrict__ Pgb, const unsigned short* __restrict__ Q1b,
                 const unsigned short* __restrict__ Q3b,
                 int* __restrict__ agg_s, int* __restrict__ agg_v,
                 float* __restrict__ cnt, int E)
{
    __shared__ __align__(16) unsigned short Ah[16 * SA2], Al[16 * SA2];
    __shared__ __align__(16) float SP[16 * SPS];
    __shared__ __align__(16) float B1[16 * SB1];
    __shared__ int ssrc[16], sgd[16], sdst[16], seid[16];

    unsigned short* PBh = Ah;      // overlay: PB == A (identical geometry)
    unsigned short* PBl = Al;
    float* B2 = SP;                // overlay: B2 in SP's first 3328 B

    const int tid = threadIdx.x, lane = tid & 63, wave = tid >> 6;
    const int e = tid & 15, q16 = tid >> 4;
    const int e0 = blockIdx.x * 16;

    const int eg_r = e0 + e;
    const int ee_r = (eg_r < E) ? eg_r : (E - 1);
    const int src_r = eidx[ee_r];
    const int dst_r = eidx[E + ee_r];

    if (q16 < 8) {
        const float4 x = ((const float4*)(es + (size_t)ee_r * 32))[q16];
        short4v hv, lv; unsigned short h, l;
        split_bf(x.x, h, l); hv[0] = h; lv[0] = l;
        split_bf(x.y, h, l); hv[1] = h; lv[1] = l;
        split_bf(x.z, h, l); hv[2] = h; lv[2] = l;
        split_bf(x.w, h, l); hv[3] = h; lv[3] = l;
        *(short4v*)(Ah + e * SA2 + 4 * q16) = hv;
        *(short4v*)(Al + e * SA2 + 4 * q16) = lv;
    }
    { const int c = 65 + q16; Ah[e * SA2 + c] = 0; Al[e * SA2 + c] = 0; }
    { const int c = 81 + q16; if (c < 96) { Ah[e * SA2 + c] = 0; Al[e * SA2 + c] = 0; } }
    {   // SP = P1[src]+P3[dst], bf16 gathers (8 bf16 = 16B per lane per row)
        const unsigned short* P1 = Pgb + (size_t)src_r * 256;
        const unsigned short* P3 = Pgb + (size_t)dst_r * 256 + 128;
        const short8 pa = *(const short8*)(P1 + 8 * q16);
        const short8 pb = *(const short8*)(P3 + 8 * q16);
        float* o = SP + e * SPS + 8 * q16;
        #pragma unroll
        for (int j = 0; j < 8; ++j)
            o[j] = bits2f((unsigned short)pa[j]) + bits2f((unsigned short)pb[j]);
    }
    if (tid < 16) {
        const int eg = e0 + tid;
        const bool ok = (eg < E);
        const int ee = ok ? eg : (E - 1);
        seid[tid] = ee;
        ssrc[tid] = eidx[ee];
        const int d = eidx[E + ee];
        sgd[tid] = d;
        sdst[tid] = ok ? d : -1;
    }
    __syncthreads();

    #pragma unroll
    for (int k = 0; k < 3; ++k) {
        const int idx = tid + k * 256;
        if (idx < 528) {
            const int h = idx >> 4, e2 = idx & 15;
            const unsigned short* q1 = Q1b + (size_t)ssrc[e2] * 100 + h * 3;
            const unsigned short* q3 = Q3b + (size_t)sgd[e2] * 100 + h * 3;
            const float* evp = ev + (size_t)seid[e2] * 3;
            const float w16 = m1_wh[h * 33 + 16];
            const float v0 = bits2f(q1[0]) + bits2f(q3[0]) + w16 * evp[0];
            const float v1 = bits2f(q1[1]) + bits2f(q3[1]) + w16 * evp[1];
            const float v2 = bits2f(q1[2]) + bits2f(q3[2]) + w16 * evp[2];
            float* o = B1 + e2 * SB1 + h * 3;
            o[0] = v0; o[1] = v1; o[2] = v2;
            const float vn = sqrtf(fmaxf(v0 * v0 + v1 * v1 + v2 * v2, EPSF));
            unsigned short hh, ll; split_bf(vn, hh, ll);
            Ah[e2 * SA2 + 32 + h] = hh; Al[e2 * SA2 + 32 + h] = ll;
        }
    }
    __syncthreads();

    float4v acc1[2] = {{0,0,0,0},{0,0,0,0}};
    kloop<3, 2, SA2>(Ah, Al, p1h, p1l, acc1, lane, wave);
    __syncthreads();

    {
        const int q = lane >> 4;
        #pragma unroll
        for (int i = 0; i < 2; ++i) {
            const int n = (wave * 2 + i) * 16 + (lane & 15);
            #pragma unroll
            for (int r = 0; r < 4; ++r) {
                const int m = q * 4 + r;
                const float x = fmaxf(acc1[i][r] + SP[m * SPS + n], 0.f);
                unsigned short h, l; split_bf(x, h, l);
                PBh[m * SBs + n] = h; PBl[m * SBs + n] = l;
            }
        }
    }
    __syncthreads();

    {
        const int o = q16;
        const float* wrow = m1_wv + o * 33;
        const float* prow = B1 + e * SB1;
        float a0 = 0.f, a1 = 0.f, a2 = 0.f;
        matvec3_v<32>(wrow, prow, a0, a1, a2);
        const float w32 = wrow[32];
        a0 = fmaf(w32, prow[96], a0); a1 = fmaf(w32, prow[97], a1); a2 = fmaf(w32, prow[98], a2);
        const float nrm = sqrtf(fmaxf(a0 * a0 + a1 * a1 + a2 * a2, EPSF));
        const float sg = 1.f / (1.f + __expf(-nrm));
        float* p2 = B2 + e * SB2 + o * 3;
        p2[0] = a0 * sg; p2[1] = a1 * sg; p2[2] = a2 * sg;
    }
    __syncthreads();

    {
        const int h = q16;
        float a0 = 0.f, a1 = 0.f, a2 = 0.f;
        matvec3_v<16>(m2_wh + h * 16, B2 + e * SB2, a0, a1, a2);
        float* o = B1 + e * SB1 + h * 3;
        o[0] = a0; o[1] = a1; o[2] = a2;
        const float vn = sqrtf(fmaxf(a0 * a0 + a1 * a1 + a2 * a2, EPSF));
        unsigned short hh, ll; split_bf(vn, hh, ll);
        PBh[e * SBs + 128 + h] = hh; PBl[e * SBs + 128 + h] = ll;
        PBh[e * SBs + 144 + h] = 0;  PBl[e * SBs + 144 + h] = 0;
    }
    __syncthreads();

    float4v acc2[2] = {{0,0,0,0},{0,0,0,0}};
    kloop<5, 2, SBs>(PBh, PBl, p2h, p2l, acc2, lane, wave);
    __syncthreads();

    {
        const int q = lane >> 4;
        #pragma unroll
        for (int i = 0; i < 2; ++i) {
            const int n = (wave * 2 + i) * 16 + (lane & 15);
            const float bias = m2_wsb[n];
            #pragma unroll
            for (int r = 0; r < 4; ++r) {
                const int m = q * 4 + r;
                const float x = fmaxf(acc2[i][r] + bias, 0.f);
                unsigned short h, l; split_bf(x, h, l);
                Ah[m * SA2 + n] = h; Al[m * SA2 + n] = l;
            }
        }
    }
    {
        const int o = q16;
        float a0 = 0.f, a1 = 0.f, a2 = 0.f;
        matvec3_v<16>(m2_wv + o * 16, B1 + e * SB1, a0, a1, a2);
        const float nrm = sqrtf(fmaxf(a0 * a0 + a1 * a1 + a2 * a2, EPSF));
        const float sg = 1.f / (1.f + __expf(-nrm));
        float* p2 = B2 + e * SB2 + o * 3;
        p2[0] = a0 * sg; p2[1] = a1 * sg; p2[2] = a2 * sg;
    }
    __syncthreads();

    {
        const int h = q16;
        float a0 = 0.f, a1 = 0.f, a2 = 0.f;
        matvec3_v<16>(m3_wh + h * 16, B2 + e * SB2, a0, a1, a2);
        float* o = B1 + e * SB1 + h * 3;
        o[0] = a0; o[1] = a1; o[2] = a2;
        const float vn = sqrtf(fmaxf(a0 * a0 + a1 * a1 + a2 * a2, EPSF));
        unsigned short hh, ll; split_bf(vn, hh, ll);
        Ah[e * SA2 + 128 + h] = hh; Al[e * SA2 + 128 + h] = ll;
        Ah[e * SA2 + 144 + h] = 0;  Al[e * SA2 + 144 + h] = 0;
    }
    __syncthreads();

    float4v acc3[2] = {{0,0,0,0},{0,0,0,0}};
    kloop<5, 2, SA2>(Ah, Al, p3h, p3l, acc3, lane, wave);
    {
        const int o = q16;
        float a0 = 0.f, a1 = 0.f, a2 = 0.f;
        matvec3_v<16>(m3_wv + o * 16, B1 + e * SB1, a0, a1, a2);
        float* p2 = B2 + e * SB2 + o * 3;
        p2[0] = a0; p2[1] = a1; p2[2] = a2;
    }
    __syncthreads();

    // E12: scatter-add (int32 fixed-point atomics -> exact, order-invariant)
    {
        const int q = lane >> 4;
        #pragma unroll
        for (int i = 0; i < 2; ++i) {
            const int n = (wave * 2 + i) * 16 + (lane & 15);
            const float bias = m3_wsb[n];
            #pragma unroll
            for (int r = 0; r < 4; ++r) {
                const int m = q * 4 + r;
                const int d = sdst[m];
                if (d >= 0)
                    atomicAdd(&agg_s[(size_t)d * 128 + n],
                              __float2int_rn((acc3[i][r] + bias) * AGG_SCALE));
            }
        }
    }
    #pragma unroll
    for (int it = 0; it < 3; ++it) {
        const int j = q16 + 16 * it;
        const int d = sdst[e];
        if (d >= 0)
            atomicAdd(&agg_v[(size_t)d * 48 + j],
                      __float2int_rn(B2[e * SB2 + j] * AGG_SCALE));
    }
    if (tid < 16 && sdst[tid] >= 0) atomicAdd(&cnt[sdst[tid]], 1.0f);
}

// ===========================================================================
// layer_normT: wave processes NE nodes (proven math, verbatim per node)
// ===========================================================================
template<int NE, int SSTR, int VSTR>
__device__ __forceinline__ void layer_normT(float* S, float* V,
    const float* __restrict__ g, const float* __restrict__ b, float* red, int lane)
{
    #pragma unroll
    for (int e = 0; e < NE; ++e) {
        float x0 = S[e * SSTR + lane], x1 = S[e * SSTR + 64 + lane];
        float sum = x0 + x1;
        #pragma unroll
        for (int off = 32; off > 0; off >>= 1) sum += __shfl_xor(sum, off, 64);
        const float mu = sum * (1.f / 128.f);
        const float d0 = x0 - mu, d1 = x1 - mu;
        float vs = d0 * d0 + d1 * d1;
        #pragma unroll
        for (int off = 32; off > 0; off >>= 1) vs += __shfl_xor(vs, off, 64);
        const float rstd = rsqrtf(vs * (1.f / 128.f) + 1e-5f);
        S[e * SSTR + lane]      = d0 * rstd * g[lane]      + b[lane];
        S[e * SSTR + 64 + lane] = d1 * rstd * g[lane + 64] + b[lane + 64];

        if (lane < 16) {
            const float a = V[e * VSTR + lane * 3], bb = V[e * VSTR + lane * 3 + 1],
                        cc = V[e * VSTR + lane * 3 + 2];
            const float vn = fmaxf(a * a + bb * bb + cc * cc, EPSF);
            red[lane]      = vn;
            red[16 + lane] = (vn > 2.f * EPSF) ? 1.f : 0.f;
        }
        __syncthreads();
        float sn = 0.f, sm = 0.f;
        #pragma unroll
        for (int i = 0; i < 16; ++i) { sn += red[i] * red[16 + i]; sm += red[16 + i]; }
        const float rvm = rsqrtf(sn / (EPSF + sm) + EPSF);
        if (lane < 48) V[e * VSTR + lane] = red[16 + lane / 3] * V[e * VSTR + lane] * rvm;
        __syncthreads();
    }
}

// ===========================================================================
// Node kernel (R12-green, verbatim): 8 nodes/block, 128 threads, 2 waves.
// ===========================================================================
constexpr int NNS  = 132;
constexpr int NNV  = 52;
constexpr int NNH  = 100;
constexpr int NA1n = 168;
constexpr int NA2n = 552;   // f2 A stride (shorts), K=544

__global__ __launch_bounds__(128)
void node_kernel(const float* __restrict__ s, const float* __restrict__ v,
                 const float* __restrict__ f1_wh, const float* __restrict__ f1_wsb,
                 const float* __restrict__ f1_wv,
                 const float* __restrict__ f2_wh, const float* __restrict__ f2_wsb,
                 const float* __restrict__ f2_wv,
                 const float* __restrict__ ln0_g, const float* __restrict__ ln0_b,
                 const float* __restrict__ ln1_g, const float* __restrict__ ln1_b,
                 const unsigned short* __restrict__ pf1h, const unsigned short* __restrict__ pf1l,
                 const unsigned short* __restrict__ pf2h, const unsigned short* __restrict__ pf2l,
                 const int* __restrict__ agg_s, const int* __restrict__ agg_v,
                 const float* __restrict__ cnt,
                 float* __restrict__ out, int N)
{
    __shared__ __align__(16) unsigned short UBh[8 * NA1n], UBl[8 * NA1n];
    __shared__ __align__(16) unsigned short UB2h[8 * NA2n], UB2l[8 * NA2n];
    __shared__ __align__(16) float S1f[8 * NNS];
    __shared__ __align__(16) float V1f[8 * NNV];
    __shared__ __align__(16) float VH[8 * NNH];
    __shared__ __align__(16) float FV[8 * NNH];
    __shared__ float red[2 * 32];

    const int tid = threadIdx.x, lane = tid & 63, wave = tid >> 6;
    const int e = tid & 7, qq = tid >> 3;
    const int n0 = blockIdx.x * 8;

    bool oks[4];
    #pragma unroll
    for (int e4 = 0; e4 < 4; ++e4) {
        const int idx = wave * 4 + e4;
        const int ng = n0 + idx;
        oks[e4] = (ng < N);
        const int n = oks[e4] ? ng : (N - 1);
        const double inv = (1.0 / (double)fmaxf(cnt[n], 1.f)) * AGG_INV;
        if (lane < 32) {
            const float4 a = ((const float4*)(s + (size_t)n * 128))[lane];
            const int4 b = ((const int4*)(agg_s + (size_t)n * 128))[lane];
            float4 r;
            r.x = (float)((double)a.x + (double)b.x * inv);
            r.y = (float)((double)a.y + (double)b.y * inv);
            r.z = (float)((double)a.z + (double)b.z * inv);
            r.w = (float)((double)a.w + (double)b.w * inv);
            ((float4*)(S1f + idx * NNS))[lane] = r;
        }
        if (lane < 12) {
            const float4 a = ((const float4*)(v + (size_t)n * 48))[lane];
            const int4 b = ((const int4*)(agg_v + (size_t)n * 48))[lane];
            float4 r;
            r.x = (float)((double)a.x + (double)b.x * inv);
            r.y = (float)((double)a.y + (double)b.y * inv);
            r.z = (float)((double)a.z + (double)b.z * inv);
            r.w = (float)((double)a.w + (double)b.w * inv);
            ((float4*)(V1f + idx * NNV))[lane] = r;
        }
    }
    __syncthreads();

    layer_normT<4, NNS, NNV>(S1f + wave * 4 * NNS, V1f + wave * 4 * NNV,
                             ln0_g, ln0_b, red + wave * 32, lane);

    {
        const float* sp = S1f + e * NNS + qq * 8;
        short8 hv, lv; unsigned short h, l;
        #pragma unroll
        for (int j = 0; j < 8; ++j) { split_bf(sp[j], h, l); hv[j] = h; lv[j] = l; }
        *(short8*)(UBh + e * NA1n + qq * 8) = hv;
        *(short8*)(UBl + e * NA1n + qq * 8) = lv;
    }
    #pragma unroll
    for (int hi = 0; hi < 2; ++hi) {
        const int h = qq + 16 * hi;
        float a0 = 0.f, a1 = 0.f, a2 = 0.f;
        matvec3_v<16>(f1_wh + h * 16, V1f + e * NNV, a0, a1, a2);
        float* o = VH + e * NNH + h * 3;
        o[0] = a0; o[1] = a1; o[2] = a2;
        const float vn = sqrtf(fmaxf(a0 * a0 + a1 * a1 + a2 * a2, EPSF));
        unsigned short hh, ll; split_bf(vn, hh, ll);
        UBh[e * NA1n + 128 + h] = hh; UBl[e * NA1n + 128 + h] = ll;
    }
    __syncthreads();

    {
        float4v acc1[16];
        #pragma unroll
        for (int i = 0; i < 16; ++i) acc1[i] = (float4v){0.f, 0.f, 0.f, 0.f};
        kloop<5, 16, NA1n>(UBh, UBl, pf1h, pf1l, acc1, lane, wave);
        const int q = lane >> 4;
        #pragma unroll
        for (int i = 0; i < 16; ++i) {
            const int n = (wave * 16 + i) * 16 + (lane & 15);
            const float bias = f1_wsb[n];
            #pragma unroll
            for (int r = 0; r < 4; ++r) {
                const int m = q * 4 + r;
                if (m < 8) {
                    const float x = fmaxf(acc1[i][r] + bias, 0.f);
                    unsigned short h, l; split_bf(x, h, l);
                    UB2h[m * NA2n + n] = h; UB2l[m * NA2n + n] = l;
                }
            }
        }
    }
    #pragma unroll
    for (int oi = 0; oi < 2; ++oi) {
        const int o = qq + 16 * oi;
        float a0 = 0.f, a1 = 0.f, a2 = 0.f;
        matvec3_v<32>(f1_wv + o * 32, VH + e * NNH, a0, a1, a2);
        const float nrm = sqrtf(fmaxf(a0 * a0 + a1 * a1 + a2 * a2, EPSF));
        const float sg = 1.f / (1.f + __expf(-nrm));
        float* p2 = FV + e * NNH + o * 3;
        p2[0] = a0 * sg; p2[1] = a1 * sg; p2[2] = a2 * sg;
    }
    __syncthreads();

    #pragma unroll
    for (int hi = 0; hi < 2; ++hi) {
        const int h = qq + 16 * hi;
        float a0 = 0.f, a1 = 0.f, a2 = 0.f;
        matvec3_v<32>(f2_wh + h * 32, FV + e * NNH, a0, a1, a2);
        float* o = VH + e * NNH + h * 3;
        o[0] = a0; o[1] = a1; o[2] = a2;
        const float vn = sqrtf(fmaxf(a0 * a0 + a1 * a1 + a2 * a2, EPSF));
        unsigned short hh, ll; split_bf(vn, hh, ll);
        UB2h[e * NA2n + 512 + h] = hh; UB2l[e * NA2n + 512 + h] = ll;
    }
    __syncthreads();

    {
        float4v acc2[4] = {{0,0,0,0},{0,0,0,0},{0,0,0,0},{0,0,0,0}};
        kloop<17, 4, NA2n, 7>(UB2h, UB2l, pf2h, pf2l, acc2, lane, wave);
        const int q = lane >> 4;
        #pragma unroll
        for (int i = 0; i < 4; ++i) {
            const int n = (wave * 4 + i) * 16 + (lane & 15);
            const float bias = f2_wsb[n];
            #pragma unroll
            for (int r = 0; r < 4; ++r) {
                const int m = q * 4 + r;
                if (m < 8) S1f[m * NNS + n] += acc2[i][r] + bias;
            }
        }
    }
    {
        const int o = qq;
        float a0 = 0.f, a1 = 0.f, a2 = 0.f;
        matvec3_v<32>(f2_wv + o * 32, VH + e * NNH, a0, a1, a2);
        float* p2 = V1f + e * NNV + o * 3;
        p2[0] += a0; p2[1] += a1; p2[2] += a2;
    }
    __syncthreads();

    layer_normT<4, NNS, NNV>(S1f + wave * 4 * NNS, V1f + wave * 4 * NNV,
                             ln1_g, ln1_b, red + wave * 32, lane);

    #pragma unroll
    for (int e4 = 0; e4 < 4; ++e4) {
        if (!oks[e4]) continue;
        const int idx = wave * 4 + e4;
        const int n = n0 + idx;
        if (lane < 32)
            ((float4*)(out + (size_t)n * 128))[lane] = ((const float4*)(S1f + idx * NNS))[lane];
        if (lane < 12)
            ((float4*)(out + (size_t)N * 128 + (size_t)n * 48))[lane] =
                ((const float4*)(V1f + idx * NNV))[lane];
    }
}

// ---------------------------------------------------------------------------
extern "C" void kernel_launch(void* const* d_in, const int* in_sizes, int n_in,
                              void* d_out, int out_size, void* d_ws, size_t ws_size,
                              hipStream_t stream)
{
    const float* s    = (const float*)d_in[0];
    const float* v    = (const float*)d_in[1];
    const int*   eidx = (const int*)d_in[2];
    const float* es   = (const float*)d_in[3];
    const float* ev   = (const float*)d_in[4];
    const float* m1_wh = (const float*)d_in[5];
    const float* m1_wsw = (const float*)d_in[6];
    const float* m1_wsb = (const float*)d_in[7];
    const float* m1_wv = (const float*)d_in[8];
    const float* m2_wh = (const float*)d_in[9];
    const float* m2_wsw = (const float*)d_in[10];
    const float* m2_wsb = (const float*)d_in[11];
    const float* m2_wv = (const float*)d_in[12];
    const float* m3_wh = (const float*)d_in[13];
    const float* m3_wsw = (const float*)d_in[14];
    const float* m3_wsb = (const float*)d_in[15];
    const float* m3_wv = (const float*)d_in[16];
    const float* f1_wh = (const float*)d_in[17];
    const float* f1_wsw = (const float*)d_in[18];
    const float* f1_wsb = (const float*)d_in[19];
    const float* f1_wv = (const float*)d_in[20];
    const float* f2_wh = (const float*)d_in[21];
    const float* f2_wsw = (const float*)d_in[22];
    const float* f2_wsb = (const float*)d_in[23];
    const float* f2_wv = (const float*)d_in[24];
    const float* ln0_g = (const float*)d_in[25];
    const float* ln0_b = (const float*)d_in[26];
    const float* ln1_g = (const float*)d_in[27];
    const float* ln1_b = (const float*)d_in[28];

    const int N = in_sizes[0] / 128;
    const int E = in_sizes[2] / 2;

    int* agg_s = (int*)d_ws;                           // N*128 i32 (Q11.20)
    int* agg_v = agg_s + (size_t)N * 128;              // N*48  i32
    float* cnt = (float*)(agg_v + (size_t)N * 48);     // N     f32
    unsigned short* pk =
        (unsigned short*)(((uintptr_t)(cnt + N) + 15) & ~(uintptr_t)15);
    const int S_P1E = 12288, S_M23 = 20480, S_MN = 32768, S_F1 = 81920, S_F2 = 69632;
    unsigned short* p1h = pk;            unsigned short* p1l = p1h + S_P1E;
    unsigned short* p2h = p1l + S_P1E;   unsigned short* p2l = p2h + S_M23;
    unsigned short* p3h = p2l + S_M23;   unsigned short* p3l = p3h + S_M23;
    unsigned short* pnh = p3l + S_M23;   unsigned short* pnl = pnh + S_MN;
    unsigned short* pf1h = pnl + S_MN;   unsigned short* pf1l = pf1h + S_F1;
    unsigned short* pf2h = pf1l + S_F1;  unsigned short* pf2l = pf2h + S_F2;
    unsigned short* Pgb =
        (unsigned short*)(((uintptr_t)(pf2l + S_F2) + 15) & ~(uintptr_t)15);
    unsigned short* Q1b = Pgb + (size_t)N * 256;
    unsigned short* Q3b = Q1b + (size_t)N * 100;

    hipMemsetAsync(d_ws, 0, (size_t)N * 177 * sizeof(int), stream);

    pack_m1e<<<dim3((12288 + 255) / 256), dim3(256), 0, stream>>>(m1_wsw, p1h, p1l);
    pack_w<<<dim3((S_M23 + 255) / 256), dim3(256), 0, stream>>>(m2_wsw, p2h, p2l, 128, 144, 5);
    pack_w<<<dim3((S_M23 + 255) / 256), dim3(256), 0, stream>>>(m3_wsw, p3h, p3l, 128, 144, 5);
    pack_m1n<<<dim3((32768 + 255) / 256), dim3(256), 0, stream>>>(m1_wsw, pnh, pnl);
    pack_w<<<dim3((S_F1 + 255) / 256), dim3(256), 0, stream>>>(f1_wsw, pf1h, pf1l, 512, 160, 5);
    pack_w<<<dim3((S_F2 + 255) / 256), dim3(256), 0, stream>>>(f2_wsw, pf2h, pf2l, 128, 544, 17);

    node_pre<<<dim3((N + 15) / 16), dim3(256), 0, stream>>>(
        s, v, m1_wh, m1_wsb, pnh, pnl, Pgb, Q1b, Q3b, N);

    edge_kernel<<<dim3((E + 15) / 16), dim3(256), 0, stream>>>(
        eidx, es, ev,
        m1_wh, m1_wv,
        m2_wh, m2_wsb, m2_wv,
        m3_wh, m3_wsb, m3_wv,
        p1h, p1l, p2h, p2l, p3h, p3l,
        Pgb, Q1b, Q3b,
        agg_s, agg_v, cnt, E);

    node_kernel<<<dim3((N + 7) / 8), dim3(128), 0, stream>>>(
        s, v,
        f1_wh, f1_wsb, f1_wv,
        f2_wh, f2_wsb, f2_wv,
        ln0_g, ln0_b, ln1_g, ln1_b,
        pf1h, pf1l, pf2h, pf2l,
        agg_s, agg_v, cnt,
        (float*)d_out, N);
}